// Round 6
// baseline (2085.060 us; speedup 1.0000x reference)
//
#include <hip/hip_runtime.h>
#include <math.h>

#define NN 100000
#define MPAD 100096
#define DD 128
#define EE 1600000
#define ET (EE + NN)
#define ND (NN * DD)

typedef short bf16x8 __attribute__((ext_vector_type(8)));
typedef float f32x4 __attribute__((ext_vector_type(4)));

static __device__ __forceinline__ unsigned short f2bf(float f) {
  unsigned int u = __float_as_uint(f);
  u += 0x7FFFu + ((u >> 16) & 1u);
  return (unsigned short)(u >> 16);
}
static __device__ __forceinline__ float bf2f(unsigned short h) {
  return __uint_as_float(((unsigned int)h) << 16);
}
static __device__ __forceinline__ float gelu_exact(float v) {
  return 0.5f * v * (1.f + erff(v * 0.7071067811865476f));
}

// ---------------- CSR build ----------------

__global__ void k_zero_int(int* __restrict__ p, int n) {
  int i = blockIdx.x * blockDim.x + threadIdx.x;
  if (i < n) p[i] = 0;
}

__global__ void k_count(const int* __restrict__ ei, int* __restrict__ deg) {
  int t = blockIdx.x * blockDim.x + threadIdx.x;
  if (t >= ET) return;
  int dst = (t < EE) ? ei[EE + t] : (t - EE);
  atomicAdd(&deg[dst], 1);
}

#define SCAN_T 256
#define SCAN_E 2048

__global__ void k_scan1(const int* __restrict__ deg, int* __restrict__ bsum) {
  __shared__ int sh[SCAN_T];
  int t = threadIdx.x;
  int base = blockIdx.x * SCAN_E + t * 8;
  int s = 0;
#pragma unroll
  for (int j = 0; j < 8; ++j) { int idx = base + j; if (idx < NN) s += deg[idx]; }
  sh[t] = s; __syncthreads();
  for (int off = SCAN_T / 2; off > 0; off >>= 1) {
    if (t < off) sh[t] += sh[t + off];
    __syncthreads();
  }
  if (t == 0) bsum[blockIdx.x] = sh[0];
}

__global__ void k_scan2(int* __restrict__ bsum, int nb, int* __restrict__ row_ptr) {
  if (threadIdx.x == 0) {
    int run = 0;
    for (int i = 0; i < nb; ++i) { int v = bsum[i]; bsum[i] = run; run += v; }
    row_ptr[NN] = run;
  }
}

__global__ void k_scan3(const int* __restrict__ deg, const int* __restrict__ bsum,
                        int* __restrict__ row_ptr) {
  __shared__ int tmp[SCAN_T];
  int t = threadIdx.x;
  int base = blockIdx.x * SCAN_E + t * 8;
  int loc[8]; int s = 0;
#pragma unroll
  for (int j = 0; j < 8; ++j) {
    loc[j] = s;
    int idx = base + j;
    int v = (idx < NN) ? deg[idx] : 0;
    s += v;
  }
  tmp[t] = s; __syncthreads();
  for (int off = 1; off < SCAN_T; off <<= 1) {
    int v = (t >= off) ? tmp[t - off] : 0;
    __syncthreads();
    tmp[t] += v;
    __syncthreads();
  }
  int excl = tmp[t] - s + bsum[blockIdx.x];
#pragma unroll
  for (int j = 0; j < 8; ++j) { int idx = base + j; if (idx < NN) row_ptr[idx] = excl + loc[j]; }
}

__global__ void k_copy_int(const int* __restrict__ a, int* __restrict__ b, int n) {
  int i = blockIdx.x * blockDim.x + threadIdx.x;
  if (i < n) b[i] = a[i];
}

__global__ void k_scatter(const int* __restrict__ ei, int* __restrict__ cursor,
                          int* __restrict__ csr_src) {
  int t = blockIdx.x * blockDim.x + threadIdx.x;
  if (t >= ET) return;
  int src, dst;
  if (t < EE) { src = ei[t]; dst = ei[EE + t]; } else { src = t - EE; dst = src; }
  int pos = atomicAdd(&cursor[dst], 1);
  csr_src[pos] = src;
}

// ---------------- weight fragment precompute (19 mats of 128x128) ----------------
// frag-major: for (mat, t, c): lane l, j -> W[t*32 + 8*(l>>4) + j][c*16 + (l&15)]
// stored at wf[mat*16384 + ((t*8+c)*64 + l)*8 + j], hi and lo split.

__global__ __launch_bounds__(256) void k_wconv(const float* __restrict__ encWl,
                                               const float* __restrict__ encWr,
                                               const float* __restrict__ decWl,
                                               const float* __restrict__ decWr,
                                               const float* __restrict__ Wmu,
                                               const float* __restrict__ Wls,
                                               const float* __restrict__ Wout,
                                               unsigned short* __restrict__ wfh,
                                               unsigned short* __restrict__ wfl) {
  int wid = (blockIdx.x * 256 + threadIdx.x) >> 6;
  int lane = threadIdx.x & 63;
  if (wid >= 19 * 32) return;
  int mat = wid >> 5;
  int sub = wid & 31;
  const float* W;
  if (mat < 4) W = encWl + (size_t)mat * 16384;
  else if (mat < 8) W = encWr + (size_t)(mat - 4) * 16384;
  else if (mat < 12) W = decWl + (size_t)(mat - 8) * 16384;
  else if (mat < 16) W = decWr + (size_t)(mat - 12) * 16384;
  else if (mat == 16) W = Wmu;
  else if (mat == 17) W = Wls;
  else W = Wout;
  int t = sub >> 3, c = sub & 7;
  int col = c * 16 + (lane & 15);
  int k0 = t * 32 + (lane >> 4) * 8;
  bf16x8 vh, vl;
#pragma unroll
  for (int j = 0; j < 8; ++j) {
    float w = W[(size_t)(k0 + j) * 128 + col];
    unsigned short h = f2bf(w);
    vh[j] = (short)h;
    vl[j] = (short)f2bf(w - bf2f(h));
  }
  size_t base = ((size_t)wid * 64 + lane) * 8;
  *(bf16x8*)(wfh + base) = vh;
  *(bf16x8*)(wfl + base) = vl;
}

// ---------------- x -> bf16 hi/lo stage ----------------

__global__ void k_xconv(const float* __restrict__ x, unsigned short* __restrict__ sh,
                        unsigned short* __restrict__ sl) {
  int i = blockIdx.x * blockDim.x + threadIdx.x;
  if (i >= MPAD * 128 / 8) return;
  size_t base = (size_t)i * 8;
  float v[8];
  if (base < (size_t)ND) {
    float4 f0 = *(const float4*)(x + base);
    float4 f1 = *(const float4*)(x + base + 4);
    v[0] = f0.x; v[1] = f0.y; v[2] = f0.z; v[3] = f0.w;
    v[4] = f1.x; v[5] = f1.y; v[6] = f1.z; v[7] = f1.w;
  } else {
#pragma unroll
    for (int j = 0; j < 8; ++j) v[j] = 0.f;
  }
  bf16x8 vh, vl;
#pragma unroll
  for (int j = 0; j < 8; ++j) {
    unsigned short h = f2bf(v[j]);
    vh[j] = (short)h;
    vl[j] = (short)f2bf(v[j] - bf2f(h));
  }
  *(bf16x8*)(sh + base) = vh;
  *(bf16x8*)(sl + base) = vl;
}

// ---------------- MFMA GEMM: split-bf16, single-W LDS stage, transposed epilogue --------
// 512 threads = 8 waves; 256 rows/block; each wave 2 row-tiles of 16.
// LDS: 64 KB weight frags (w_h | w_l), reused as 128x132 fp32 transpose buffer.
// MODE 0: C = A@W (+bias if non-null), coalesced float4 stores.
// MODE 1: ls = min(A@W + bias, 10); C = ls; z = mu + eps*exp(ls); writes z fp32 and
//         bf16 hi/lo stage Zh/Zl. (Zh/Zl may alias Ah/Al: per block, reads of its own
//         rows complete before its writes; blocks touch disjoint rows.)
template <int MODE>
__global__ __launch_bounds__(512, 3) void k_mm2(const unsigned short* Ah,
                                                const unsigned short* Al,
                                                const unsigned short* __restrict__ whg,
                                                const unsigned short* __restrict__ wlg,
                                                const float* __restrict__ bias,
                                                float* __restrict__ C,
                                                const float* __restrict__ mu,
                                                const float* __restrict__ eps,
                                                float* __restrict__ Z,
                                                unsigned short* Zh,
                                                unsigned short* Zl) {
  __shared__ float ldsbuf[128 * 132];  // 67.6 KB: weights (64 KB) then transpose tile
  int tid = threadIdx.x;
  {
    int4* d = (int4*)ldsbuf;
    const int4* s1 = (const int4*)whg;
    const int4* s2 = (const int4*)wlg;
#pragma unroll
    for (int i = 0; i < 4; ++i) {
      d[tid + i * 512] = s1[tid + i * 512];
      d[2048 + tid + i * 512] = s2[tid + i * 512];
    }
  }

  int wv = tid >> 6, lane = tid & 63;
  int lrow = lane & 15, lk = lane >> 4;
  int rbase = blockIdx.x * 256 + wv * 32;

  // A fragments (issued before the barrier so they overlap the staging)
  bf16x8 a_h[2][4], a_l[2][4];
#pragma unroll
  for (int n = 0; n < 2; ++n) {
    const unsigned short* ap = Ah + (size_t)(rbase + n * 16 + lrow) * 128 + lk * 8;
    const unsigned short* alp = Al + (size_t)(rbase + n * 16 + lrow) * 128 + lk * 8;
#pragma unroll
    for (int t = 0; t < 4; ++t) {
      a_h[n][t] = *(const bf16x8*)(ap + t * 32);
      a_l[n][t] = *(const bf16x8*)(alp + t * 32);
    }
  }
  __syncthreads();

  const unsigned short* lw = (const unsigned short*)ldsbuf;
  f32x4 acc[2][8];
#pragma unroll
  for (int n = 0; n < 2; ++n)
#pragma unroll
    for (int c = 0; c < 8; ++c) acc[n][c] = (f32x4){0.f, 0.f, 0.f, 0.f};

#pragma unroll
  for (int t = 0; t < 4; ++t) {
#pragma unroll
    for (int c = 0; c < 8; ++c) {
      int fo = ((t * 8 + c) * 64 + lane) * 8;
      bf16x8 wh = *(const bf16x8*)(lw + fo);
      bf16x8 wl = *(const bf16x8*)(lw + 16384 + fo);
#pragma unroll
      for (int n = 0; n < 2; ++n) {
        acc[n][c] = __builtin_amdgcn_mfma_f32_16x16x32_bf16(a_h[n][t], wh, acc[n][c], 0, 0, 0);
        acc[n][c] = __builtin_amdgcn_mfma_f32_16x16x32_bf16(a_l[n][t], wh, acc[n][c], 0, 0, 0);
        acc[n][c] = __builtin_amdgcn_mfma_f32_16x16x32_bf16(a_h[n][t], wl, acc[n][c], 0, 0, 0);
      }
    }
  }
  __syncthreads();  // weights no longer needed; LDS becomes transpose buffer

#pragma unroll
  for (int half = 0; half < 2; ++half) {
    if ((wv >> 2) == half) {
      int lrb = (wv & 3) * 32;
#pragma unroll
      for (int n = 0; n < 2; ++n)
#pragma unroll
        for (int c = 0; c < 8; ++c)
#pragma unroll
          for (int r = 0; r < 4; ++r)
            ldsbuf[(lrb + n * 16 + lk * 4 + r) * 132 + c * 16 + lrow] = acc[n][c][r];
    }
    __syncthreads();
    {
      int lr = tid >> 2, cb = (tid & 3) << 5;
      int grow = blockIdx.x * 256 + half * 128 + lr;
      if (grow < NN) {
        size_t o = (size_t)grow * 128 + cb;
        const float* srcp = &ldsbuf[lr * 132 + cb];
#pragma unroll
        for (int i = 0; i < 8; ++i) {
          float4 v = *(const float4*)(srcp + i * 4);
          if (MODE == 0) {
            if (bias != nullptr) {
              float4 b4 = *(const float4*)&bias[cb + i * 4];
              v.x += b4.x; v.y += b4.y; v.z += b4.z; v.w += b4.w;
            }
            *(float4*)&C[o + i * 4] = v;
          } else {
            float4 b4 = *(const float4*)&bias[cb + i * 4];
            float4 ls;
            ls.x = fminf(v.x + b4.x, 10.f);
            ls.y = fminf(v.y + b4.y, 10.f);
            ls.z = fminf(v.z + b4.z, 10.f);
            ls.w = fminf(v.w + b4.w, 10.f);
            *(float4*)&C[o + i * 4] = ls;
            float4 m4 = *(const float4*)&mu[o + i * 4];
            float4 e4 = *(const float4*)&eps[o + i * 4];
            float4 z4;
            z4.x = fmaf(e4.x, expf(ls.x), m4.x);
            z4.y = fmaf(e4.y, expf(ls.y), m4.y);
            z4.z = fmaf(e4.z, expf(ls.z), m4.z);
            z4.w = fmaf(e4.w, expf(ls.w), m4.w);
            *(float4*)&Z[o + i * 4] = z4;
            ushort4 hh, ll;
            hh.x = f2bf(z4.x); ll.x = f2bf(z4.x - bf2f(hh.x));
            hh.y = f2bf(z4.y); ll.y = f2bf(z4.y - bf2f(hh.y));
            hh.z = f2bf(z4.z); ll.z = f2bf(z4.z - bf2f(hh.z));
            hh.w = f2bf(z4.w); ll.w = f2bf(z4.w - bf2f(hh.w));
            *(ushort4*)&Zh[o + i * 4] = hh;
            *(ushort4*)&Zl[o + i * 4] = ll;
          }
        }
      }
    }
    __syncthreads();
  }
}

// ---------------- GATv2 aggregation: wave/row, 4 groups of 16 lanes, 1 edge/group ----------------

__global__ __launch_bounds__(256) void k_gat_agg(const float* __restrict__ gxl,
                                                 const float* __restrict__ gxr,
                                                 const float* __restrict__ att,
                                                 const float* __restrict__ bias,
                                                 const int* __restrict__ row_ptr,
                                                 const int* __restrict__ csr_src,
                                                 unsigned short* __restrict__ sh,
                                                 unsigned short* __restrict__ sl) {
  int gid = blockIdx.x * blockDim.x + threadIdx.x;
  int row = gid >> 6;
  int lane = gid & 63;
  if (row >= NN) return;
  int g = lane >> 4, j = lane & 15;
  int dbase = j * 8;

  float4 a0 = *(const float4*)&att[dbase];
  float4 a1 = *(const float4*)&att[dbase + 4];
  const float* xrp = &gxr[(size_t)row * 128 + dbase];
  float4 r0 = *(const float4*)xrp;
  float4 r1 = *(const float4*)(xrp + 4);

  float m = -INFINITY, d = 0.f;
  float acc[8] = {0.f, 0.f, 0.f, 0.f, 0.f, 0.f, 0.f, 0.f};
  int p0 = row_ptr[row], p1 = row_ptr[row + 1];

  for (int p = p0 + g; p < p1; p += 4) {
    int s = csr_src[p];
    const float* xlp = &gxl[(size_t)s * 128 + dbase];
    float4 v0 = *(const float4*)xlp;
    float4 v1 = *(const float4*)(xlp + 4);

    float t0, e;
    t0 = v0.x + r0.x; t0 = fmaxf(t0, 0.2f * t0); e = t0 * a0.x;
    t0 = v0.y + r0.y; t0 = fmaxf(t0, 0.2f * t0); e = fmaf(t0, a0.y, e);
    t0 = v0.z + r0.z; t0 = fmaxf(t0, 0.2f * t0); e = fmaf(t0, a0.z, e);
    t0 = v0.w + r0.w; t0 = fmaxf(t0, 0.2f * t0); e = fmaf(t0, a0.w, e);
    t0 = v1.x + r1.x; t0 = fmaxf(t0, 0.2f * t0); e = fmaf(t0, a1.x, e);
    t0 = v1.y + r1.y; t0 = fmaxf(t0, 0.2f * t0); e = fmaf(t0, a1.y, e);
    t0 = v1.z + r1.z; t0 = fmaxf(t0, 0.2f * t0); e = fmaf(t0, a1.z, e);
    t0 = v1.w + r1.w; t0 = fmaxf(t0, 0.2f * t0); e = fmaf(t0, a1.w, e);

    e += __shfl_xor(e, 1);
    e += __shfl_xor(e, 2);
    e += __shfl_xor(e, 4);
    e += __shfl_xor(e, 8);

    float mn = fmaxf(m, e);
    float scl = __expf(m - mn);
    float w = __expf(e - mn);
    d = d * scl + w;
    acc[0] = acc[0] * scl + w * v0.x;
    acc[1] = acc[1] * scl + w * v0.y;
    acc[2] = acc[2] * scl + w * v0.z;
    acc[3] = acc[3] * scl + w * v0.w;
    acc[4] = acc[4] * scl + w * v1.x;
    acc[5] = acc[5] * scl + w * v1.y;
    acc[6] = acc[6] * scl + w * v1.z;
    acc[7] = acc[7] * scl + w * v1.w;
    m = mn;
  }

  // merge 4 groups (flash-style)
  float mo = fmaxf(m, __shfl_xor(m, 16));
  mo = fmaxf(mo, __shfl_xor(mo, 32));
  float scl = __expf(m - mo);  // 0 for empty groups (m = -inf)
  d *= scl;
  d += __shfl_xor(d, 16);
  d += __shfl_xor(d, 32);
#pragma unroll
  for (int k = 0; k < 8; ++k) {
    acc[k] *= scl;
    acc[k] += __shfl_xor(acc[k], 16);
    acc[k] += __shfl_xor(acc[k], 32);
  }

  if (g == 0) {
    float inv = 1.f / d;
    float4 b0 = *(const float4*)&bias[dbase];
    float4 b1v = *(const float4*)&bias[dbase + 4];
    float bb[8] = {b0.x, b0.y, b0.z, b0.w, b1v.x, b1v.y, b1v.z, b1v.w};
    bf16x8 vh, vl;
#pragma unroll
    for (int k = 0; k < 8; ++k) {
      float h = gelu_exact(acc[k] * inv + bb[k]);
      unsigned short hi = f2bf(h);
      vh[k] = (short)hi;
      vl[k] = (short)f2bf(h - bf2f(hi));
    }
    *(bf16x8*)(sh + (size_t)row * 128 + dbase) = vh;
    *(bf16x8*)(sl + (size_t)row * 128 + dbase) = vl;
  }
}

// ---------------- degree head ----------------

__global__ __launch_bounds__(256) void k_degp(const float* __restrict__ z,
                                              const float* __restrict__ Wd,
                                              const float* __restrict__ bd,
                                              float* __restrict__ outp) {
  int gid = blockIdx.x * blockDim.x + threadIdx.x;
  int row = gid >> 6;
  int lane = gid & 63;
  if (row >= NN) return;
  float2 zz = *(const float2*)&z[(size_t)row * 128 + lane * 2];
  float2 ww = *(const float2*)&Wd[lane * 2];
  float s = zz.x * ww.x + zz.y * ww.y;
#pragma unroll
  for (int off = 32; off > 0; off >>= 1) s += __shfl_xor(s, off);
  if (lane == 0) outp[row] = s + bd[0];
}

// ---------------- host ----------------

static inline char* take(char*& p, size_t bytes) {
  char* r = p;
  p += (bytes + 255) & ~(size_t)255;
  return r;
}

extern "C" void kernel_launch(void* const* d_in, const int* in_sizes, int n_in,
                              void* d_out, int out_size, void* d_ws, size_t ws_size,
                              hipStream_t stream) {
  const float* x      = (const float*)d_in[0];
  const int*   ei     = (const int*)d_in[1];
  const float* eps    = (const float*)d_in[2];
  const float* encWl  = (const float*)d_in[3];
  const float* encWr  = (const float*)d_in[4];
  const float* encAtt = (const float*)d_in[5];
  const float* encB   = (const float*)d_in[6];
  const float* decWl  = (const float*)d_in[7];
  const float* decWr  = (const float*)d_in[8];
  const float* decAtt = (const float*)d_in[9];
  const float* decB   = (const float*)d_in[10];
  const float* W_mu   = (const float*)d_in[11];
  const float* b_mu   = (const float*)d_in[12];
  const float* W_ls   = (const float*)d_in[13];
  const float* b_ls   = (const float*)d_in[14];
  const float* W_out  = (const float*)d_in[15];
  const float* b_out  = (const float*)d_in[16];
  const float* W_deg  = (const float*)d_in[17];
  const float* b_deg  = (const float*)d_in[18];

  float* out    = (float*)d_out;
  float* x_rec  = out;
  float* z      = out + (size_t)ND;
  float* mu     = out + (size_t)2 * ND;
  float* logstd = out + (size_t)3 * ND;
  float* degp   = out + (size_t)4 * ND;

  char* p = (char*)d_ws;
  int* deg     = (int*)take(p, (size_t)NN * 4);
  int* row_ptr = (int*)take(p, (size_t)(NN + 1) * 4);
  int* cursor  = (int*)take(p, (size_t)NN * 4);
  int* bsum    = (int*)take(p, 64 * 4);
  int* csr_src = (int*)take(p, (size_t)ET * 4);
  float* gxl   = (float*)take(p, (size_t)ND * 4);
  float* gxr   = (float*)take(p, (size_t)ND * 4);
  unsigned short* stgh = (unsigned short*)take(p, (size_t)MPAD * 128 * 2);
  unsigned short* stgl = (unsigned short*)take(p, (size_t)MPAD * 128 * 2);
  unsigned short* wfh  = (unsigned short*)take(p, (size_t)19 * 16384 * 2);
  unsigned short* wfl  = (unsigned short*)take(p, (size_t)19 * 16384 * 2);

  const int nScan = (NN + SCAN_E - 1) / SCAN_E;   // 49
  const int gN    = (NN + 255) / 256;             // 391
  const int gET   = (ET + 255) / 256;             // 6641
  const int gMM   = MPAD / 256;                   // 391
  const int gWave = (NN * 64 + 255) / 256;        // 25000
  const int gXC   = (MPAD * 128 / 8 + 255) / 256; // 6256

  // CSR build
  k_zero_int<<<gN, 256, 0, stream>>>(deg, NN);
  k_count<<<gET, 256, 0, stream>>>(ei, deg);
  k_scan1<<<nScan, SCAN_T, 0, stream>>>(deg, bsum);
  k_scan2<<<1, 64, 0, stream>>>(bsum, nScan, row_ptr);
  k_scan3<<<nScan, SCAN_T, 0, stream>>>(deg, bsum, row_ptr);
  k_copy_int<<<gN, 256, 0, stream>>>(row_ptr, cursor, NN);
  k_scatter<<<gET, 256, 0, stream>>>(ei, cursor, csr_src);

  // weight frags + x stage
  k_wconv<<<152, 256, 0, stream>>>(encWl, encWr, decWl, decWr, W_mu, W_ls, W_out, wfh, wfl);
  k_xconv<<<gXC, 256, 0, stream>>>(x, stgh, stgl);

  const size_t WM = 16384;
  // encoder
  for (int l = 0; l < 4; ++l) {
    k_mm2<0><<<gMM, 512, 0, stream>>>(stgh, stgl,
                                      wfh + (size_t)l * WM, wfl + (size_t)l * WM,
                                      nullptr, gxl, nullptr, nullptr, nullptr,
                                      nullptr, nullptr);
    k_mm2<0><<<gMM, 512, 0, stream>>>(stgh, stgl,
                                      wfh + (size_t)(4 + l) * WM, wfl + (size_t)(4 + l) * WM,
                                      nullptr, gxr, nullptr, nullptr, nullptr,
                                      nullptr, nullptr);
    k_gat_agg<<<gWave, 256, 0, stream>>>(gxl, gxr, encAtt + (size_t)l * DD,
                                         encB + (size_t)l * DD, row_ptr, csr_src, stgh, stgl);
  }

  // heads: mu, then ls + z (+ bf16 stage of z)
  k_mm2<0><<<gMM, 512, 0, stream>>>(stgh, stgl,
                                    wfh + (size_t)16 * WM, wfl + (size_t)16 * WM,
                                    b_mu, mu, nullptr, nullptr, nullptr,
                                    nullptr, nullptr);
  k_mm2<1><<<gMM, 512, 0, stream>>>(stgh, stgl,
                                    wfh + (size_t)17 * WM, wfl + (size_t)17 * WM,
                                    b_ls, logstd, mu, eps, z, stgh, stgl);

  // decoder
  for (int l = 0; l < 4; ++l) {
    k_mm2<0><<<gMM, 512, 0, stream>>>(stgh, stgl,
                                      wfh + (size_t)(8 + l) * WM, wfl + (size_t)(8 + l) * WM,
                                      nullptr, gxl, nullptr, nullptr, nullptr,
                                      nullptr, nullptr);
    k_mm2<0><<<gMM, 512, 0, stream>>>(stgh, stgl,
                                      wfh + (size_t)(12 + l) * WM, wfl + (size_t)(12 + l) * WM,
                                      nullptr, gxr, nullptr, nullptr, nullptr,
                                      nullptr, nullptr);
    k_gat_agg<<<gWave, 256, 0, stream>>>(gxl, gxr, decAtt + (size_t)l * DD,
                                         decB + (size_t)l * DD, row_ptr, csr_src, stgh, stgl);
  }

  // outputs
  k_mm2<0><<<gMM, 512, 0, stream>>>(stgh, stgl,
                                    wfh + (size_t)18 * WM, wfl + (size_t)18 * WM,
                                    b_out, x_rec, nullptr, nullptr, nullptr,
                                    nullptr, nullptr);
  k_degp<<<gWave, 256, 0, stream>>>(z, W_deg, b_deg, degp);
}

// Round 7
// 1610.472 us; speedup vs baseline: 1.2947x; 1.2947x over previous
//
#include <hip/hip_runtime.h>
#include <math.h>

#define NN 100000
#define MPAD 100096
#define DD 128
#define EE 1600000
#define ET (EE + NN)
#define ND (NN * DD)

typedef short bf16x8 __attribute__((ext_vector_type(8)));
typedef float f32x4 __attribute__((ext_vector_type(4)));

static __device__ __forceinline__ unsigned short f2bf(float f) {
  unsigned int u = __float_as_uint(f);
  u += 0x7FFFu + ((u >> 16) & 1u);
  return (unsigned short)(u >> 16);
}
static __device__ __forceinline__ float bf2f(unsigned short h) {
  return __uint_as_float(((unsigned int)h) << 16);
}
static __device__ __forceinline__ float gelu_exact(float v) {
  return 0.5f * v * (1.f + erff(v * 0.7071067811865476f));
}

// ---------------- CSR build ----------------

__global__ void k_zero_int(int* __restrict__ p, int n) {
  int i = blockIdx.x * blockDim.x + threadIdx.x;
  if (i < n) p[i] = 0;
}

__global__ void k_count(const int* __restrict__ ei, int* __restrict__ deg) {
  int t = blockIdx.x * blockDim.x + threadIdx.x;
  if (t >= ET) return;
  int dst = (t < EE) ? ei[EE + t] : (t - EE);
  atomicAdd(&deg[dst], 1);
}

#define SCAN_T 256
#define SCAN_E 2048

__global__ void k_scan1(const int* __restrict__ deg, int* __restrict__ bsum) {
  __shared__ int sh[SCAN_T];
  int t = threadIdx.x;
  int base = blockIdx.x * SCAN_E + t * 8;
  int s = 0;
#pragma unroll
  for (int j = 0; j < 8; ++j) { int idx = base + j; if (idx < NN) s += deg[idx]; }
  sh[t] = s; __syncthreads();
  for (int off = SCAN_T / 2; off > 0; off >>= 1) {
    if (t < off) sh[t] += sh[t + off];
    __syncthreads();
  }
  if (t == 0) bsum[blockIdx.x] = sh[0];
}

__global__ void k_scan2(int* __restrict__ bsum, int nb, int* __restrict__ row_ptr) {
  if (threadIdx.x == 0) {
    int run = 0;
    for (int i = 0; i < nb; ++i) { int v = bsum[i]; bsum[i] = run; run += v; }
    row_ptr[NN] = run;
  }
}

__global__ void k_scan3(const int* __restrict__ deg, const int* __restrict__ bsum,
                        int* __restrict__ row_ptr) {
  __shared__ int tmp[SCAN_T];
  int t = threadIdx.x;
  int base = blockIdx.x * SCAN_E + t * 8;
  int loc[8]; int s = 0;
#pragma unroll
  for (int j = 0; j < 8; ++j) {
    loc[j] = s;
    int idx = base + j;
    int v = (idx < NN) ? deg[idx] : 0;
    s += v;
  }
  tmp[t] = s; __syncthreads();
  for (int off = 1; off < SCAN_T; off <<= 1) {
    int v = (t >= off) ? tmp[t - off] : 0;
    __syncthreads();
    tmp[t] += v;
    __syncthreads();
  }
  int excl = tmp[t] - s + bsum[blockIdx.x];
#pragma unroll
  for (int j = 0; j < 8; ++j) { int idx = base + j; if (idx < NN) row_ptr[idx] = excl + loc[j]; }
}

__global__ void k_copy_int(const int* __restrict__ a, int* __restrict__ b, int n) {
  int i = blockIdx.x * blockDim.x + threadIdx.x;
  if (i < n) b[i] = a[i];
}

__global__ void k_scatter(const int* __restrict__ ei, int* __restrict__ cursor,
                          int* __restrict__ csr_src) {
  int t = blockIdx.x * blockDim.x + threadIdx.x;
  if (t >= ET) return;
  int src, dst;
  if (t < EE) { src = ei[t]; dst = ei[EE + t]; } else { src = t - EE; dst = src; }
  int pos = atomicAdd(&cursor[dst], 1);
  csr_src[pos] = src;
}

// ---------------- weight fragment precompute (19 mats of 128x128) ----------------
// frag-major: for (mat, t, c): lane l, j -> W[t*32 + 8*(l>>4) + j][c*16 + (l&15)]
// stored at wf[mat*16384 + ((t*8+c)*64 + l)*8 + j], hi and lo split.

__global__ __launch_bounds__(256) void k_wconv(const float* __restrict__ encWl,
                                               const float* __restrict__ encWr,
                                               const float* __restrict__ decWl,
                                               const float* __restrict__ decWr,
                                               const float* __restrict__ Wmu,
                                               const float* __restrict__ Wls,
                                               const float* __restrict__ Wout,
                                               unsigned short* __restrict__ wfh,
                                               unsigned short* __restrict__ wfl) {
  int wid = (blockIdx.x * 256 + threadIdx.x) >> 6;
  int lane = threadIdx.x & 63;
  if (wid >= 19 * 32) return;
  int mat = wid >> 5;
  int sub = wid & 31;
  const float* W;
  if (mat < 4) W = encWl + (size_t)mat * 16384;
  else if (mat < 8) W = encWr + (size_t)(mat - 4) * 16384;
  else if (mat < 12) W = decWl + (size_t)(mat - 8) * 16384;
  else if (mat < 16) W = decWr + (size_t)(mat - 12) * 16384;
  else if (mat == 16) W = Wmu;
  else if (mat == 17) W = Wls;
  else W = Wout;
  int t = sub >> 3, c = sub & 7;
  int col = c * 16 + (lane & 15);
  int k0 = t * 32 + (lane >> 4) * 8;
  bf16x8 vh, vl;
#pragma unroll
  for (int j = 0; j < 8; ++j) {
    float w = W[(size_t)(k0 + j) * 128 + col];
    unsigned short h = f2bf(w);
    vh[j] = (short)h;
    vl[j] = (short)f2bf(w - bf2f(h));
  }
  size_t base = ((size_t)wid * 64 + lane) * 8;
  *(bf16x8*)(wfh + base) = vh;
  *(bf16x8*)(wfl + base) = vl;
}

// ---------------- x -> bf16 hi/lo stage ----------------

__global__ void k_xconv(const float* __restrict__ x, unsigned short* __restrict__ sh,
                        unsigned short* __restrict__ sl) {
  int i = blockIdx.x * blockDim.x + threadIdx.x;
  if (i >= MPAD * 128 / 8) return;
  size_t base = (size_t)i * 8;
  float v[8];
  if (base < (size_t)ND) {
    float4 f0 = *(const float4*)(x + base);
    float4 f1 = *(const float4*)(x + base + 4);
    v[0] = f0.x; v[1] = f0.y; v[2] = f0.z; v[3] = f0.w;
    v[4] = f1.x; v[5] = f1.y; v[6] = f1.z; v[7] = f1.w;
  } else {
#pragma unroll
    for (int j = 0; j < 8; ++j) v[j] = 0.f;
  }
  bf16x8 vh, vl;
#pragma unroll
  for (int j = 0; j < 8; ++j) {
    unsigned short h = f2bf(v[j]);
    vh[j] = (short)h;
    vl[j] = (short)f2bf(v[j] - bf2f(h));
  }
  *(bf16x8*)(sh + base) = vh;
  *(bf16x8*)(sl + base) = vl;
}

// ---------------- layer dual GEMM: bf16 out, 2-term split (a_h+a_l)*w ----------------
// 512 thr = 8 waves, 128 rows/block (1 tile of 16/wave). LDS: w1|w2 (64 KB) then
// 128x132 f32 transpose buffer. Outputs gxl, gxr bf16 (MPAD rows, no guard).

__global__ __launch_bounds__(512, 4) void k_mmL(const unsigned short* __restrict__ Ah,
                                                const unsigned short* __restrict__ Al,
                                                const unsigned short* __restrict__ w1,
                                                const unsigned short* __restrict__ w2,
                                                unsigned short* __restrict__ o1,
                                                unsigned short* __restrict__ o2) {
  __shared__ float lds[128 * 132];  // 67.6 KB
  unsigned short* lw = (unsigned short*)lds;
  int tid = threadIdx.x;
  {
    int4* d = (int4*)lw;
    const int4* s1 = (const int4*)w1;
    const int4* s2 = (const int4*)w2;
#pragma unroll
    for (int i = 0; i < 4; ++i) {
      d[tid + i * 512] = s1[tid + i * 512];
      d[2048 + tid + i * 512] = s2[tid + i * 512];
    }
  }
  int wv = tid >> 6, lane = tid & 63;
  int lrow = lane & 15, lk = lane >> 4;
  int rbase = blockIdx.x * 128 + wv * 16;

  bf16x8 a_h[4], a_l[4];
  const unsigned short* ap = Ah + (size_t)(rbase + lrow) * 128 + lk * 8;
  const unsigned short* alp = Al + (size_t)(rbase + lrow) * 128 + lk * 8;
#pragma unroll
  for (int t = 0; t < 4; ++t) {
    a_h[t] = *(const bf16x8*)(ap + t * 32);
    a_l[t] = *(const bf16x8*)(alp + t * 32);
  }
  __syncthreads();

  f32x4 acc1[8], acc2[8];
#pragma unroll
  for (int c = 0; c < 8; ++c) {
    acc1[c] = (f32x4){0.f, 0.f, 0.f, 0.f};
    acc2[c] = (f32x4){0.f, 0.f, 0.f, 0.f};
  }
#pragma unroll
  for (int t = 0; t < 4; ++t) {
#pragma unroll
    for (int c = 0; c < 8; ++c) {
      int fo = ((t * 8 + c) * 64 + lane) * 8;
      bf16x8 wf1 = *(const bf16x8*)(lw + fo);
      bf16x8 wf2 = *(const bf16x8*)(lw + 16384 + fo);
      acc1[c] = __builtin_amdgcn_mfma_f32_16x16x32_bf16(a_h[t], wf1, acc1[c], 0, 0, 0);
      acc1[c] = __builtin_amdgcn_mfma_f32_16x16x32_bf16(a_l[t], wf1, acc1[c], 0, 0, 0);
      acc2[c] = __builtin_amdgcn_mfma_f32_16x16x32_bf16(a_h[t], wf2, acc2[c], 0, 0, 0);
      acc2[c] = __builtin_amdgcn_mfma_f32_16x16x32_bf16(a_l[t], wf2, acc2[c], 0, 0, 0);
    }
  }
  __syncthreads();  // weights dead; LDS becomes transpose buffer

  int lr = tid >> 2, cb = (tid & 3) << 5;
  size_t o = ((size_t)blockIdx.x * 128 + lr) * 128 + cb;

#pragma unroll
  for (int out = 0; out < 2; ++out) {
#pragma unroll
    for (int c = 0; c < 8; ++c)
#pragma unroll
      for (int r = 0; r < 4; ++r)
        lds[(wv * 16 + lk * 4 + r) * 132 + c * 16 + lrow] = out ? acc2[c][r] : acc1[c][r];
    __syncthreads();
    {
      unsigned short* dst = out ? o2 : o1;
      const float* sp = &lds[lr * 132 + cb];
#pragma unroll
      for (int i = 0; i < 4; ++i) {
        union { unsigned short u[8]; int4 v; } pk;
#pragma unroll
        for (int j = 0; j < 8; ++j) pk.u[j] = f2bf(sp[i * 8 + j]);
        *(int4*)&dst[o + i * 8] = pk.v;
      }
    }
    __syncthreads();
  }
}

// ---------------- head kernel: mu, logstd, z, z-stage, degree pred ----------------
// 3-term split both GEMMs. LDS: 4 planes (128 KB), transpose reuses first 67.6 KB.

__global__ __launch_bounds__(512, 2) void k_mmH(const unsigned short* Ah,
                                                const unsigned short* Al,
                                                const unsigned short* __restrict__ w1h,
                                                const unsigned short* __restrict__ w1l,
                                                const unsigned short* __restrict__ w2h,
                                                const unsigned short* __restrict__ w2l,
                                                const float* __restrict__ b1,
                                                const float* __restrict__ b2,
                                                const float* __restrict__ eps,
                                                const float* __restrict__ Wd,
                                                const float* __restrict__ bd,
                                                float* __restrict__ mu,
                                                float* __restrict__ logstd,
                                                float* __restrict__ Z,
                                                unsigned short* Zh,
                                                unsigned short* Zl,
                                                float* __restrict__ degp) {
  __shared__ unsigned short lw[4 * 16384];  // 128 KB
  float* tb = (float*)lw;                   // transpose view (67.6 KB used)
  int tid = threadIdx.x;
  {
    int4* d = (int4*)lw;
#pragma unroll
    for (int i = 0; i < 4; ++i) {
      d[tid + i * 512] = ((const int4*)w1h)[tid + i * 512];
      d[2048 + tid + i * 512] = ((const int4*)w1l)[tid + i * 512];
      d[4096 + tid + i * 512] = ((const int4*)w2h)[tid + i * 512];
      d[6144 + tid + i * 512] = ((const int4*)w2l)[tid + i * 512];
    }
  }
  int wv = tid >> 6, lane = tid & 63;
  int lrow = lane & 15, lk = lane >> 4;
  int rbase = blockIdx.x * 128 + wv * 16;

  bf16x8 a_h[4], a_l[4];
  const unsigned short* ap = Ah + (size_t)(rbase + lrow) * 128 + lk * 8;
  const unsigned short* alp = Al + (size_t)(rbase + lrow) * 128 + lk * 8;
#pragma unroll
  for (int t = 0; t < 4; ++t) {
    a_h[t] = *(const bf16x8*)(ap + t * 32);
    a_l[t] = *(const bf16x8*)(alp + t * 32);
  }
  __syncthreads();

  f32x4 acc1[8], acc2[8];
#pragma unroll
  for (int c = 0; c < 8; ++c) {
    acc1[c] = (f32x4){0.f, 0.f, 0.f, 0.f};
    acc2[c] = (f32x4){0.f, 0.f, 0.f, 0.f};
  }
#pragma unroll
  for (int t = 0; t < 4; ++t) {
#pragma unroll
    for (int c = 0; c < 8; ++c) {
      int fo = ((t * 8 + c) * 64 + lane) * 8;
      bf16x8 wh = *(const bf16x8*)(lw + fo);
      bf16x8 wl = *(const bf16x8*)(lw + 16384 + fo);
      acc1[c] = __builtin_amdgcn_mfma_f32_16x16x32_bf16(a_h[t], wh, acc1[c], 0, 0, 0);
      acc1[c] = __builtin_amdgcn_mfma_f32_16x16x32_bf16(a_l[t], wh, acc1[c], 0, 0, 0);
      acc1[c] = __builtin_amdgcn_mfma_f32_16x16x32_bf16(a_h[t], wl, acc1[c], 0, 0, 0);
      bf16x8 wh2 = *(const bf16x8*)(lw + 32768 + fo);
      bf16x8 wl2 = *(const bf16x8*)(lw + 49152 + fo);
      acc2[c] = __builtin_amdgcn_mfma_f32_16x16x32_bf16(a_h[t], wh2, acc2[c], 0, 0, 0);
      acc2[c] = __builtin_amdgcn_mfma_f32_16x16x32_bf16(a_l[t], wh2, acc2[c], 0, 0, 0);
      acc2[c] = __builtin_amdgcn_mfma_f32_16x16x32_bf16(a_h[t], wl2, acc2[c], 0, 0, 0);
    }
  }
  __syncthreads();

  int lr = tid >> 2, cb = (tid & 3) << 5;
  int grow = blockIdx.x * 128 + lr;
  size_t o = (size_t)grow * 128 + cb;

  // round 1: mu
#pragma unroll
  for (int c = 0; c < 8; ++c)
#pragma unroll
    for (int r = 0; r < 4; ++r)
      tb[(wv * 16 + lk * 4 + r) * 132 + c * 16 + lrow] = acc1[c][r];
  __syncthreads();
  if (grow < NN) {
    const float* sp = &tb[lr * 132 + cb];
#pragma unroll
    for (int i = 0; i < 8; ++i) {
      float4 v = *(const float4*)(sp + i * 4);
      float4 b4 = *(const float4*)&b1[cb + i * 4];
      v.x += b4.x; v.y += b4.y; v.z += b4.z; v.w += b4.w;
      *(float4*)&mu[o + i * 4] = v;
    }
  }
  __syncthreads();
  // round 2: logstd, z, stage, degree
#pragma unroll
  for (int c = 0; c < 8; ++c)
#pragma unroll
    for (int r = 0; r < 4; ++r)
      tb[(wv * 16 + lk * 4 + r) * 132 + c * 16 + lrow] = acc2[c][r];
  __syncthreads();
  float s_deg = 0.f;
  if (grow < NN) {
    const float* sp = &tb[lr * 132 + cb];
#pragma unroll
    for (int i = 0; i < 8; ++i) {
      float4 v = *(const float4*)(sp + i * 4);
      float4 b4 = *(const float4*)&b2[cb + i * 4];
      float4 ls;
      ls.x = fminf(v.x + b4.x, 10.f);
      ls.y = fminf(v.y + b4.y, 10.f);
      ls.z = fminf(v.z + b4.z, 10.f);
      ls.w = fminf(v.w + b4.w, 10.f);
      *(float4*)&logstd[o + i * 4] = ls;
      float4 m4 = *(const float4*)&mu[o + i * 4];
      float4 e4 = *(const float4*)&eps[o + i * 4];
      float4 z4;
      z4.x = fmaf(e4.x, expf(ls.x), m4.x);
      z4.y = fmaf(e4.y, expf(ls.y), m4.y);
      z4.z = fmaf(e4.z, expf(ls.z), m4.z);
      z4.w = fmaf(e4.w, expf(ls.w), m4.w);
      *(float4*)&Z[o + i * 4] = z4;
      ushort4 hh, ll;
      hh.x = f2bf(z4.x); ll.x = f2bf(z4.x - bf2f(hh.x));
      hh.y = f2bf(z4.y); ll.y = f2bf(z4.y - bf2f(hh.y));
      hh.z = f2bf(z4.z); ll.z = f2bf(z4.z - bf2f(hh.z));
      hh.w = f2bf(z4.w); ll.w = f2bf(z4.w - bf2f(hh.w));
      *(ushort4*)&Zh[o + i * 4] = hh;
      *(ushort4*)&Zl[o + i * 4] = ll;
      float4 wd = *(const float4*)&Wd[cb + i * 4];
      s_deg += z4.x * wd.x + z4.y * wd.y + z4.z * wd.z + z4.w * wd.w;
    }
  }
  s_deg += __shfl_xor(s_deg, 1);
  s_deg += __shfl_xor(s_deg, 2);
  if (grow < NN && (tid & 3) == 0) degp[grow] = s_deg + bd[0];
}

// ---------------- output GEMM: x_rec = A@W + b, 3-term split, fp32 out ----------------

__global__ __launch_bounds__(512, 4) void k_mmO(const unsigned short* __restrict__ Ah,
                                                const unsigned short* __restrict__ Al,
                                                const unsigned short* __restrict__ wh,
                                                const unsigned short* __restrict__ wl,
                                                const float* __restrict__ bias,
                                                float* __restrict__ C) {
  __shared__ float lds[128 * 132];
  unsigned short* lw = (unsigned short*)lds;
  int tid = threadIdx.x;
  {
    int4* d = (int4*)lw;
#pragma unroll
    for (int i = 0; i < 4; ++i) {
      d[tid + i * 512] = ((const int4*)wh)[tid + i * 512];
      d[2048 + tid + i * 512] = ((const int4*)wl)[tid + i * 512];
    }
  }
  int wv = tid >> 6, lane = tid & 63;
  int lrow = lane & 15, lk = lane >> 4;
  int rbase = blockIdx.x * 128 + wv * 16;

  bf16x8 a_h[4], a_l[4];
  const unsigned short* ap = Ah + (size_t)(rbase + lrow) * 128 + lk * 8;
  const unsigned short* alp = Al + (size_t)(rbase + lrow) * 128 + lk * 8;
#pragma unroll
  for (int t = 0; t < 4; ++t) {
    a_h[t] = *(const bf16x8*)(ap + t * 32);
    a_l[t] = *(const bf16x8*)(alp + t * 32);
  }
  __syncthreads();

  f32x4 acc[8];
#pragma unroll
  for (int c = 0; c < 8; ++c) acc[c] = (f32x4){0.f, 0.f, 0.f, 0.f};
#pragma unroll
  for (int t = 0; t < 4; ++t) {
#pragma unroll
    for (int c = 0; c < 8; ++c) {
      int fo = ((t * 8 + c) * 64 + lane) * 8;
      bf16x8 whf = *(const bf16x8*)(lw + fo);
      bf16x8 wlf = *(const bf16x8*)(lw + 16384 + fo);
      acc[c] = __builtin_amdgcn_mfma_f32_16x16x32_bf16(a_h[t], whf, acc[c], 0, 0, 0);
      acc[c] = __builtin_amdgcn_mfma_f32_16x16x32_bf16(a_l[t], whf, acc[c], 0, 0, 0);
      acc[c] = __builtin_amdgcn_mfma_f32_16x16x32_bf16(a_h[t], wlf, acc[c], 0, 0, 0);
    }
  }
  __syncthreads();

#pragma unroll
  for (int c = 0; c < 8; ++c)
#pragma unroll
    for (int r = 0; r < 4; ++r)
      lds[(wv * 16 + lk * 4 + r) * 132 + c * 16 + lrow] = acc[c][r];
  __syncthreads();
  int lr = tid >> 2, cb = (tid & 3) << 5;
  int grow = blockIdx.x * 128 + lr;
  if (grow < NN) {
    size_t o = (size_t)grow * 128 + cb;
    const float* sp = &lds[lr * 132 + cb];
#pragma unroll
    for (int i = 0; i < 8; ++i) {
      float4 v = *(const float4*)(sp + i * 4);
      float4 b4 = *(const float4*)&bias[cb + i * 4];
      v.x += b4.x; v.y += b4.y; v.z += b4.z; v.w += b4.w;
      *(float4*)&C[o + i * 4] = v;
    }
  }
}

// ---------------- GATv2 aggregation: wave/row, 4x16 lanes, bf16 gathers ----------------

__global__ __launch_bounds__(256) void k_gat_agg(const unsigned short* __restrict__ gxl,
                                                 const unsigned short* __restrict__ gxr,
                                                 const float* __restrict__ att,
                                                 const float* __restrict__ bias,
                                                 const int* __restrict__ row_ptr,
                                                 const int* __restrict__ csr_src,
                                                 unsigned short* __restrict__ sh,
                                                 unsigned short* __restrict__ sl) {
  int gid = blockIdx.x * blockDim.x + threadIdx.x;
  int row = gid >> 6;
  int lane = gid & 63;
  if (row >= NN) return;
  int g = lane >> 4, j = lane & 15;
  int dbase = j * 8;

  float a[8], r[8];
  {
    float4 a0 = *(const float4*)&att[dbase];
    float4 a1 = *(const float4*)&att[dbase + 4];
    a[0] = a0.x; a[1] = a0.y; a[2] = a0.z; a[3] = a0.w;
    a[4] = a1.x; a[5] = a1.y; a[6] = a1.z; a[7] = a1.w;
    bf16x8 rv = *(const bf16x8*)&gxr[(size_t)row * 128 + dbase];
#pragma unroll
    for (int k = 0; k < 8; ++k) r[k] = bf2f((unsigned short)rv[k]);
  }

  float m = -INFINITY, d = 0.f;
  float acc[8] = {0.f, 0.f, 0.f, 0.f, 0.f, 0.f, 0.f, 0.f};
  int p0 = row_ptr[row], p1 = row_ptr[row + 1];

  for (int p = p0 + g; p < p1; p += 4) {
    int s = csr_src[p];
    bf16x8 xv = *(const bf16x8*)&gxl[(size_t)s * 128 + dbase];
    float v[8];
#pragma unroll
    for (int k = 0; k < 8; ++k) v[k] = bf2f((unsigned short)xv[k]);

    float e = 0.f;
#pragma unroll
    for (int k = 0; k < 8; ++k) {
      float t0 = v[k] + r[k];
      t0 = fmaxf(t0, 0.2f * t0);
      e = fmaf(t0, a[k], e);
    }
    e += __shfl_xor(e, 1);
    e += __shfl_xor(e, 2);
    e += __shfl_xor(e, 4);
    e += __shfl_xor(e, 8);

    float mn = fmaxf(m, e);
    float scl = __expf(m - mn);
    float w = __expf(e - mn);
    d = d * scl + w;
#pragma unroll
    for (int k = 0; k < 8; ++k) acc[k] = acc[k] * scl + w * v[k];
    m = mn;
  }

  float mo = fmaxf(m, __shfl_xor(m, 16));
  mo = fmaxf(mo, __shfl_xor(mo, 32));
  float scl = __expf(m - mo);
  d *= scl;
  d += __shfl_xor(d, 16);
  d += __shfl_xor(d, 32);
#pragma unroll
  for (int k = 0; k < 8; ++k) {
    acc[k] *= scl;
    acc[k] += __shfl_xor(acc[k], 16);
    acc[k] += __shfl_xor(acc[k], 32);
  }

  if (g == 0) {
    float inv = 1.f / d;
    float4 b0 = *(const float4*)&bias[dbase];
    float4 b1v = *(const float4*)&bias[dbase + 4];
    float bb[8] = {b0.x, b0.y, b0.z, b0.w, b1v.x, b1v.y, b1v.z, b1v.w};
    bf16x8 vh, vl;
#pragma unroll
    for (int k = 0; k < 8; ++k) {
      float h = gelu_exact(acc[k] * inv + bb[k]);
      unsigned short hi = f2bf(h);
      vh[k] = (short)hi;
      vl[k] = (short)f2bf(h - bf2f(hi));
    }
    *(bf16x8*)(sh + (size_t)row * 128 + dbase) = vh;
    *(bf16x8*)(sl + (size_t)row * 128 + dbase) = vl;
  }
}

// ---------------- host ----------------

static inline char* take(char*& p, size_t bytes) {
  char* r = p;
  p += (bytes + 255) & ~(size_t)255;
  return r;
}

extern "C" void kernel_launch(void* const* d_in, const int* in_sizes, int n_in,
                              void* d_out, int out_size, void* d_ws, size_t ws_size,
                              hipStream_t stream) {
  const float* x      = (const float*)d_in[0];
  const int*   ei     = (const int*)d_in[1];
  const float* eps    = (const float*)d_in[2];
  const float* encWl  = (const float*)d_in[3];
  const float* encWr  = (const float*)d_in[4];
  const float* encAtt = (const float*)d_in[5];
  const float* encB   = (const float*)d_in[6];
  const float* decWl  = (const float*)d_in[7];
  const float* decWr  = (const float*)d_in[8];
  const float* decAtt = (const float*)d_in[9];
  const float* decB   = (const float*)d_in[10];
  const float* W_mu   = (const float*)d_in[11];
  const float* b_mu   = (const float*)d_in[12];
  const float* W_ls   = (const float*)d_in[13];
  const float* b_ls   = (const float*)d_in[14];
  const float* W_out  = (const float*)d_in[15];
  const float* b_out  = (const float*)d_in[16];
  const float* W_deg  = (const float*)d_in[17];
  const float* b_deg  = (const float*)d_in[18];

  float* out    = (float*)d_out;
  float* x_rec  = out;
  float* z      = out + (size_t)ND;
  float* mu     = out + (size_t)2 * ND;
  float* logstd = out + (size_t)3 * ND;
  float* degp   = out + (size_t)4 * ND;

  char* p = (char*)d_ws;
  int* deg     = (int*)take(p, (size_t)NN * 4);
  int* row_ptr = (int*)take(p, (size_t)(NN + 1) * 4);
  int* cursor  = (int*)take(p, (size_t)NN * 4);
  int* bsum    = (int*)take(p, 64 * 4);
  int* csr_src = (int*)take(p, (size_t)ET * 4);
  unsigned short* gxl  = (unsigned short*)take(p, (size_t)MPAD * 128 * 2);
  unsigned short* gxr  = (unsigned short*)take(p, (size_t)MPAD * 128 * 2);
  unsigned short* stgh = (unsigned short*)take(p, (size_t)MPAD * 128 * 2);
  unsigned short* stgl = (unsigned short*)take(p, (size_t)MPAD * 128 * 2);
  unsigned short* wfh  = (unsigned short*)take(p, (size_t)19 * 16384 * 2);
  unsigned short* wfl  = (unsigned short*)take(p, (size_t)19 * 16384 * 2);

  const int nScan = (NN + SCAN_E - 1) / SCAN_E;   // 49
  const int gN    = (NN + 255) / 256;             // 391
  const int gET   = (ET + 255) / 256;             // 6641
  const int gMM   = MPAD / 128;                   // 782
  const int gWave = (NN * 64 + 255) / 256;        // 25000
  const int gXC   = (MPAD * 128 / 8 + 255) / 256; // 6256

  // CSR build
  k_zero_int<<<gN, 256, 0, stream>>>(deg, NN);
  k_count<<<gET, 256, 0, stream>>>(ei, deg);
  k_scan1<<<nScan, SCAN_T, 0, stream>>>(deg, bsum);
  k_scan2<<<1, 64, 0, stream>>>(bsum, nScan, row_ptr);
  k_scan3<<<nScan, SCAN_T, 0, stream>>>(deg, bsum, row_ptr);
  k_copy_int<<<gN, 256, 0, stream>>>(row_ptr, cursor, NN);
  k_scatter<<<gET, 256, 0, stream>>>(ei, cursor, csr_src);

  // weight frags + x stage
  k_wconv<<<152, 256, 0, stream>>>(encWl, encWr, decWl, decWr, W_mu, W_ls, W_out, wfh, wfl);
  k_xconv<<<gXC, 256, 0, stream>>>(x, stgh, stgl);

  const size_t WM = 16384;
  // encoder
  for (int l = 0; l < 4; ++l) {
    k_mmL<<<gMM, 512, 0, stream>>>(stgh, stgl,
                                   wfh + (size_t)l * WM, wfh + (size_t)(4 + l) * WM,
                                   gxl, gxr);
    k_gat_agg<<<gWave, 256, 0, stream>>>(gxl, gxr, encAtt + (size_t)l * DD,
                                         encB + (size_t)l * DD, row_ptr, csr_src, stgh, stgl);
  }

  // heads: mu, logstd, z, z-stage, degree head (fused)
  k_mmH<<<gMM, 512, 0, stream>>>(stgh, stgl,
                                 wfh + (size_t)16 * WM, wfl + (size_t)16 * WM,
                                 wfh + (size_t)17 * WM, wfl + (size_t)17 * WM,
                                 b_mu, b_ls, eps, W_deg, b_deg,
                                 mu, logstd, z, stgh, stgl, degp);

  // decoder
  for (int l = 0; l < 4; ++l) {
    k_mmL<<<gMM, 512, 0, stream>>>(stgh, stgl,
                                   wfh + (size_t)(8 + l) * WM, wfh + (size_t)(12 + l) * WM,
                                   gxl, gxr);
    k_gat_agg<<<gWave, 256, 0, stream>>>(gxl, gxr, decAtt + (size_t)l * DD,
                                         decB + (size_t)l * DD, row_ptr, csr_src, stgh, stgl);
  }

  // x_rec
  k_mmO<<<gMM, 512, 0, stream>>>(stgh, stgl,
                                 wfh + (size_t)18 * WM, wfl + (size_t)18 * WM,
                                 b_out, x_rec);
}

// Round 8
// 1494.421 us; speedup vs baseline: 1.3952x; 1.0777x over previous
//
#include <hip/hip_runtime.h>
#include <math.h>

#define NN 100000
#define MPAD 100096
#define DD 128
#define EE 1600000
#define ET (EE + NN)
#define ND (NN * DD)

typedef short bf16x8 __attribute__((ext_vector_type(8)));
typedef float f32x4 __attribute__((ext_vector_type(4)));

static __device__ __forceinline__ unsigned short f2bf(float f) {
  unsigned int u = __float_as_uint(f);
  u += 0x7FFFu + ((u >> 16) & 1u);
  return (unsigned short)(u >> 16);
}
static __device__ __forceinline__ float bf2f(unsigned short h) {
  return __uint_as_float(((unsigned int)h) << 16);
}
static __device__ __forceinline__ float gelu_exact(float v) {
  return 0.5f * v * (1.f + erff(v * 0.7071067811865476f));
}

// ---------------- CSR build ----------------

__global__ void k_zero_int(int* __restrict__ p, int n) {
  int i = blockIdx.x * blockDim.x + threadIdx.x;
  if (i < n) p[i] = 0;
}

__global__ void k_count(const int* __restrict__ ei, int* __restrict__ deg) {
  int t = blockIdx.x * blockDim.x + threadIdx.x;
  if (t >= ET) return;
  int dst = (t < EE) ? ei[EE + t] : (t - EE);
  atomicAdd(&deg[dst], 1);
}

#define SCAN_T 256
#define SCAN_E 2048

__global__ void k_scan1(const int* __restrict__ deg, int* __restrict__ bsum) {
  __shared__ int sh[SCAN_T];
  int t = threadIdx.x;
  int base = blockIdx.x * SCAN_E + t * 8;
  int s = 0;
#pragma unroll
  for (int j = 0; j < 8; ++j) { int idx = base + j; if (idx < NN) s += deg[idx]; }
  sh[t] = s; __syncthreads();
  for (int off = SCAN_T / 2; off > 0; off >>= 1) {
    if (t < off) sh[t] += sh[t + off];
    __syncthreads();
  }
  if (t == 0) bsum[blockIdx.x] = sh[0];
}

__global__ void k_scan2(int* __restrict__ bsum, int nb, int* __restrict__ row_ptr) {
  if (threadIdx.x == 0) {
    int run = 0;
    for (int i = 0; i < nb; ++i) { int v = bsum[i]; bsum[i] = run; run += v; }
    row_ptr[NN] = run;
  }
}

__global__ void k_scan3(const int* __restrict__ deg, const int* __restrict__ bsum,
                        int* __restrict__ row_ptr) {
  __shared__ int tmp[SCAN_T];
  int t = threadIdx.x;
  int base = blockIdx.x * SCAN_E + t * 8;
  int loc[8]; int s = 0;
#pragma unroll
  for (int j = 0; j < 8; ++j) {
    loc[j] = s;
    int idx = base + j;
    int v = (idx < NN) ? deg[idx] : 0;
    s += v;
  }
  tmp[t] = s; __syncthreads();
  for (int off = 1; off < SCAN_T; off <<= 1) {
    int v = (t >= off) ? tmp[t - off] : 0;
    __syncthreads();
    tmp[t] += v;
    __syncthreads();
  }
  int excl = tmp[t] - s + bsum[blockIdx.x];
#pragma unroll
  for (int j = 0; j < 8; ++j) { int idx = base + j; if (idx < NN) row_ptr[idx] = excl + loc[j]; }
}

__global__ void k_copy_int(const int* __restrict__ a, int* __restrict__ b, int n) {
  int i = blockIdx.x * blockDim.x + threadIdx.x;
  if (i < n) b[i] = a[i];
}

__global__ void k_scatter(const int* __restrict__ ei, int* __restrict__ cursor,
                          int* __restrict__ csr_src) {
  int t = blockIdx.x * blockDim.x + threadIdx.x;
  if (t >= ET) return;
  int src, dst;
  if (t < EE) { src = ei[t]; dst = ei[EE + t]; } else { src = t - EE; dst = src; }
  int pos = atomicAdd(&cursor[dst], 1);
  csr_src[pos] = src;
}

// ---------------- weight fragment precompute (19 mats of 128x128) ----------------

__global__ __launch_bounds__(256) void k_wconv(const float* __restrict__ encWl,
                                               const float* __restrict__ encWr,
                                               const float* __restrict__ decWl,
                                               const float* __restrict__ decWr,
                                               const float* __restrict__ Wmu,
                                               const float* __restrict__ Wls,
                                               const float* __restrict__ Wout,
                                               unsigned short* __restrict__ wfh,
                                               unsigned short* __restrict__ wfl) {
  int wid = (blockIdx.x * 256 + threadIdx.x) >> 6;
  int lane = threadIdx.x & 63;
  if (wid >= 19 * 32) return;
  int mat = wid >> 5;
  int sub = wid & 31;
  const float* W;
  if (mat < 4) W = encWl + (size_t)mat * 16384;
  else if (mat < 8) W = encWr + (size_t)(mat - 4) * 16384;
  else if (mat < 12) W = decWl + (size_t)(mat - 8) * 16384;
  else if (mat < 16) W = decWr + (size_t)(mat - 12) * 16384;
  else if (mat == 16) W = Wmu;
  else if (mat == 17) W = Wls;
  else W = Wout;
  int t = sub >> 3, c = sub & 7;
  int col = c * 16 + (lane & 15);
  int k0 = t * 32 + (lane >> 4) * 8;
  bf16x8 vh, vl;
#pragma unroll
  for (int j = 0; j < 8; ++j) {
    float w = W[(size_t)(k0 + j) * 128 + col];
    unsigned short h = f2bf(w);
    vh[j] = (short)h;
    vl[j] = (short)f2bf(w - bf2f(h));
  }
  size_t base = ((size_t)wid * 64 + lane) * 8;
  *(bf16x8*)(wfh + base) = vh;
  *(bf16x8*)(wfl + base) = vl;
}

// ---------------- x -> bf16 stage (hi only) ----------------

__global__ void k_xconv(const float* __restrict__ x, unsigned short* __restrict__ sh) {
  int i = blockIdx.x * blockDim.x + threadIdx.x;
  if (i >= MPAD * 128 / 8) return;
  size_t base = (size_t)i * 8;
  float v[8];
  if (base < (size_t)ND) {
    float4 f0 = *(const float4*)(x + base);
    float4 f1 = *(const float4*)(x + base + 4);
    v[0] = f0.x; v[1] = f0.y; v[2] = f0.z; v[3] = f0.w;
    v[4] = f1.x; v[5] = f1.y; v[6] = f1.z; v[7] = f1.w;
  } else {
#pragma unroll
    for (int j = 0; j < 8; ++j) v[j] = 0.f;
  }
  bf16x8 vh;
#pragma unroll
  for (int j = 0; j < 8; ++j) vh[j] = (short)f2bf(v[j]);
  *(bf16x8*)(sh + base) = vh;
}

// ---------------- layer dual GEMM: 1-term bf16, bf16 out ----------------
// 512 thr = 8 waves, 128 rows/block. LDS: w1|w2 hi planes (64 KB) then transpose.

__global__ __launch_bounds__(512, 4) void k_mmL(const unsigned short* __restrict__ Ah,
                                                const unsigned short* __restrict__ w1,
                                                const unsigned short* __restrict__ w2,
                                                unsigned short* __restrict__ o1,
                                                unsigned short* __restrict__ o2) {
  __shared__ float lds[128 * 132];  // 67.6 KB
  unsigned short* lw = (unsigned short*)lds;
  int tid = threadIdx.x;
  {
    int4* d = (int4*)lw;
    const int4* s1 = (const int4*)w1;
    const int4* s2 = (const int4*)w2;
#pragma unroll
    for (int i = 0; i < 4; ++i) {
      d[tid + i * 512] = s1[tid + i * 512];
      d[2048 + tid + i * 512] = s2[tid + i * 512];
    }
  }
  int wv = tid >> 6, lane = tid & 63;
  int lrow = lane & 15, lk = lane >> 4;
  int rbase = blockIdx.x * 128 + wv * 16;

  bf16x8 a_h[4];
  const unsigned short* ap = Ah + (size_t)(rbase + lrow) * 128 + lk * 8;
#pragma unroll
  for (int t = 0; t < 4; ++t) a_h[t] = *(const bf16x8*)(ap + t * 32);
  __syncthreads();

  f32x4 acc1[8], acc2[8];
#pragma unroll
  for (int c = 0; c < 8; ++c) {
    acc1[c] = (f32x4){0.f, 0.f, 0.f, 0.f};
    acc2[c] = (f32x4){0.f, 0.f, 0.f, 0.f};
  }
#pragma unroll
  for (int t = 0; t < 4; ++t) {
#pragma unroll
    for (int c = 0; c < 8; ++c) {
      int fo = ((t * 8 + c) * 64 + lane) * 8;
      bf16x8 wf1 = *(const bf16x8*)(lw + fo);
      bf16x8 wf2 = *(const bf16x8*)(lw + 16384 + fo);
      acc1[c] = __builtin_amdgcn_mfma_f32_16x16x32_bf16(a_h[t], wf1, acc1[c], 0, 0, 0);
      acc2[c] = __builtin_amdgcn_mfma_f32_16x16x32_bf16(a_h[t], wf2, acc2[c], 0, 0, 0);
    }
  }
  __syncthreads();  // weights dead; LDS becomes transpose buffer

  int lr = tid >> 2, cb = (tid & 3) << 5;
  size_t o = ((size_t)blockIdx.x * 128 + lr) * 128 + cb;

#pragma unroll
  for (int out = 0; out < 2; ++out) {
#pragma unroll
    for (int c = 0; c < 8; ++c)
#pragma unroll
      for (int r = 0; r < 4; ++r)
        lds[(wv * 16 + lk * 4 + r) * 132 + c * 16 + lrow] = out ? acc2[c][r] : acc1[c][r];
    __syncthreads();
    {
      unsigned short* dst = out ? o2 : o1;
      const float* sp = &lds[lr * 132 + cb];
#pragma unroll
      for (int i = 0; i < 4; ++i) {
        union { unsigned short u[8]; int4 v; } pk;
#pragma unroll
        for (int j = 0; j < 8; ++j) pk.u[j] = f2bf(sp[i * 8 + j]);
        *(int4*)&dst[o + i * 8] = pk.v;
      }
    }
    __syncthreads();
  }
}

// ---------------- head kernel: mu, logstd, z, z-stage(hi), degree pred ----------------
// 3-term split both GEMMs; sequential weight staging (64 KB); mu via LDS (no re-read).

__global__ __launch_bounds__(512, 3) void k_mmH(const unsigned short* Ah,
                                                const unsigned short* Al,
                                                const unsigned short* __restrict__ w1h,
                                                const unsigned short* __restrict__ w1l,
                                                const unsigned short* __restrict__ w2h,
                                                const unsigned short* __restrict__ w2l,
                                                const float* __restrict__ b1,
                                                const float* __restrict__ b2,
                                                const float* __restrict__ eps,
                                                const float* __restrict__ Wd,
                                                const float* __restrict__ bd,
                                                float* __restrict__ mu,
                                                float* __restrict__ logstd,
                                                float* __restrict__ Z,
                                                unsigned short* Zh,
                                                float* __restrict__ degp) {
  __shared__ float lds[128 * 132];  // 67.6 KB; first 64 KB = weight planes
  unsigned short* lw = (unsigned short*)lds;
  int tid = threadIdx.x;
  int wv = tid >> 6, lane = tid & 63;
  int lrow = lane & 15, lk = lane >> 4;
  int rbase = blockIdx.x * 128 + wv * 16;

  // stage W1 (hi|lo)
  {
    int4* d = (int4*)lw;
#pragma unroll
    for (int i = 0; i < 4; ++i) {
      d[tid + i * 512] = ((const int4*)w1h)[tid + i * 512];
      d[2048 + tid + i * 512] = ((const int4*)w1l)[tid + i * 512];
    }
  }
  bf16x8 a_h[4], a_l[4];
  const unsigned short* ap = Ah + (size_t)(rbase + lrow) * 128 + lk * 8;
  const unsigned short* alp = Al + (size_t)(rbase + lrow) * 128 + lk * 8;
#pragma unroll
  for (int t = 0; t < 4; ++t) {
    a_h[t] = *(const bf16x8*)(ap + t * 32);
    a_l[t] = *(const bf16x8*)(alp + t * 32);
  }
  __syncthreads();

  f32x4 acc1[8];
#pragma unroll
  for (int c = 0; c < 8; ++c) acc1[c] = (f32x4){0.f, 0.f, 0.f, 0.f};
#pragma unroll
  for (int t = 0; t < 4; ++t) {
#pragma unroll
    for (int c = 0; c < 8; ++c) {
      int fo = ((t * 8 + c) * 64 + lane) * 8;
      bf16x8 wh = *(const bf16x8*)(lw + fo);
      bf16x8 wl = *(const bf16x8*)(lw + 16384 + fo);
      acc1[c] = __builtin_amdgcn_mfma_f32_16x16x32_bf16(a_h[t], wh, acc1[c], 0, 0, 0);
      acc1[c] = __builtin_amdgcn_mfma_f32_16x16x32_bf16(a_l[t], wh, acc1[c], 0, 0, 0);
      acc1[c] = __builtin_amdgcn_mfma_f32_16x16x32_bf16(a_h[t], wl, acc1[c], 0, 0, 0);
    }
  }
  __syncthreads();  // all waves done with W1

  // stage W2 (hi|lo)
  {
    int4* d = (int4*)lw;
#pragma unroll
    for (int i = 0; i < 4; ++i) {
      d[tid + i * 512] = ((const int4*)w2h)[tid + i * 512];
      d[2048 + tid + i * 512] = ((const int4*)w2l)[tid + i * 512];
    }
  }
  __syncthreads();

  f32x4 acc2[8];
#pragma unroll
  for (int c = 0; c < 8; ++c) acc2[c] = (f32x4){0.f, 0.f, 0.f, 0.f};
#pragma unroll
  for (int t = 0; t < 4; ++t) {
#pragma unroll
    for (int c = 0; c < 8; ++c) {
      int fo = ((t * 8 + c) * 64 + lane) * 8;
      bf16x8 wh = *(const bf16x8*)(lw + fo);
      bf16x8 wl = *(const bf16x8*)(lw + 16384 + fo);
      acc2[c] = __builtin_amdgcn_mfma_f32_16x16x32_bf16(a_h[t], wh, acc2[c], 0, 0, 0);
      acc2[c] = __builtin_amdgcn_mfma_f32_16x16x32_bf16(a_l[t], wh, acc2[c], 0, 0, 0);
      acc2[c] = __builtin_amdgcn_mfma_f32_16x16x32_bf16(a_h[t], wl, acc2[c], 0, 0, 0);
    }
  }
  __syncthreads();  // weights dead; LDS = transpose buffer

  int lr = tid >> 2, cb = (tid & 3) << 5;
  int grow = blockIdx.x * 128 + lr;
  size_t o = (size_t)grow * 128 + cb;

  // round 1: mu -> LDS -> (regs + global)
#pragma unroll
  for (int c = 0; c < 8; ++c)
#pragma unroll
    for (int r = 0; r < 4; ++r)
      lds[(wv * 16 + lk * 4 + r) * 132 + c * 16 + lrow] = acc1[c][r];
  __syncthreads();
  float4 mureg[8];
  if (grow < NN) {
    const float* sp = &lds[lr * 132 + cb];
#pragma unroll
    for (int i = 0; i < 8; ++i) {
      float4 v = *(const float4*)(sp + i * 4);
      float4 b4 = *(const float4*)&b1[cb + i * 4];
      v.x += b4.x; v.y += b4.y; v.z += b4.z; v.w += b4.w;
      mureg[i] = v;
      *(float4*)&mu[o + i * 4] = v;
    }
  }
  __syncthreads();
  // round 2: logstd, z, z-stage(hi), degree
#pragma unroll
  for (int c = 0; c < 8; ++c)
#pragma unroll
    for (int r = 0; r < 4; ++r)
      lds[(wv * 16 + lk * 4 + r) * 132 + c * 16 + lrow] = acc2[c][r];
  __syncthreads();
  float s_deg = 0.f;
  if (grow < NN) {
    const float* sp = &lds[lr * 132 + cb];
#pragma unroll
    for (int i = 0; i < 8; ++i) {
      float4 v = *(const float4*)(sp + i * 4);
      float4 b4 = *(const float4*)&b2[cb + i * 4];
      float4 ls;
      ls.x = fminf(v.x + b4.x, 10.f);
      ls.y = fminf(v.y + b4.y, 10.f);
      ls.z = fminf(v.z + b4.z, 10.f);
      ls.w = fminf(v.w + b4.w, 10.f);
      *(float4*)&logstd[o + i * 4] = ls;
      float4 e4 = *(const float4*)&eps[o + i * 4];
      float4 z4;
      z4.x = fmaf(e4.x, expf(ls.x), mureg[i].x);
      z4.y = fmaf(e4.y, expf(ls.y), mureg[i].y);
      z4.z = fmaf(e4.z, expf(ls.z), mureg[i].z);
      z4.w = fmaf(e4.w, expf(ls.w), mureg[i].w);
      *(float4*)&Z[o + i * 4] = z4;
      ushort4 hh;
      hh.x = f2bf(z4.x); hh.y = f2bf(z4.y); hh.z = f2bf(z4.z); hh.w = f2bf(z4.w);
      *(ushort4*)&Zh[o + i * 4] = hh;
      float4 wd = *(const float4*)&Wd[cb + i * 4];
      s_deg += z4.x * wd.x + z4.y * wd.y + z4.z * wd.z + z4.w * wd.w;
    }
  }
  s_deg += __shfl_xor(s_deg, 1);
  s_deg += __shfl_xor(s_deg, 2);
  if (grow < NN && (tid & 3) == 0) degp[grow] = s_deg + bd[0];
}

// ---------------- output GEMM: x_rec = A@W + b, 3-term split, fp32 out ----------------

__global__ __launch_bounds__(512, 4) void k_mmO(const unsigned short* __restrict__ Ah,
                                                const unsigned short* __restrict__ Al,
                                                const unsigned short* __restrict__ wh,
                                                const unsigned short* __restrict__ wl,
                                                const float* __restrict__ bias,
                                                float* __restrict__ C) {
  __shared__ float lds[128 * 132];
  unsigned short* lw = (unsigned short*)lds;
  int tid = threadIdx.x;
  {
    int4* d = (int4*)lw;
#pragma unroll
    for (int i = 0; i < 4; ++i) {
      d[tid + i * 512] = ((const int4*)wh)[tid + i * 512];
      d[2048 + tid + i * 512] = ((const int4*)wl)[tid + i * 512];
    }
  }
  int wv = tid >> 6, lane = tid & 63;
  int lrow = lane & 15, lk = lane >> 4;
  int rbase = blockIdx.x * 128 + wv * 16;

  bf16x8 a_h[4], a_l[4];
  const unsigned short* ap = Ah + (size_t)(rbase + lrow) * 128 + lk * 8;
  const unsigned short* alp = Al + (size_t)(rbase + lrow) * 128 + lk * 8;
#pragma unroll
  for (int t = 0; t < 4; ++t) {
    a_h[t] = *(const bf16x8*)(ap + t * 32);
    a_l[t] = *(const bf16x8*)(alp + t * 32);
  }
  __syncthreads();

  f32x4 acc[8];
#pragma unroll
  for (int c = 0; c < 8; ++c) acc[c] = (f32x4){0.f, 0.f, 0.f, 0.f};
#pragma unroll
  for (int t = 0; t < 4; ++t) {
#pragma unroll
    for (int c = 0; c < 8; ++c) {
      int fo = ((t * 8 + c) * 64 + lane) * 8;
      bf16x8 whf = *(const bf16x8*)(lw + fo);
      bf16x8 wlf = *(const bf16x8*)(lw + 16384 + fo);
      acc[c] = __builtin_amdgcn_mfma_f32_16x16x32_bf16(a_h[t], whf, acc[c], 0, 0, 0);
      acc[c] = __builtin_amdgcn_mfma_f32_16x16x32_bf16(a_l[t], whf, acc[c], 0, 0, 0);
      acc[c] = __builtin_amdgcn_mfma_f32_16x16x32_bf16(a_h[t], wlf, acc[c], 0, 0, 0);
    }
  }
  __syncthreads();

#pragma unroll
  for (int c = 0; c < 8; ++c)
#pragma unroll
    for (int r = 0; r < 4; ++r)
      lds[(wv * 16 + lk * 4 + r) * 132 + c * 16 + lrow] = acc[c][r];
  __syncthreads();
  int lr = tid >> 2, cb = (tid & 3) << 5;
  int grow = blockIdx.x * 128 + lr;
  if (grow < NN) {
    size_t o = (size_t)grow * 128 + cb;
    const float* sp = &lds[lr * 132 + cb];
#pragma unroll
    for (int i = 0; i < 8; ++i) {
      float4 v = *(const float4*)(sp + i * 4);
      float4 b4 = *(const float4*)&bias[cb + i * 4];
      v.x += b4.x; v.y += b4.y; v.z += b4.z; v.w += b4.w;
      *(float4*)&C[o + i * 4] = v;
    }
  }
}

// ---------------- GATv2 aggregation: wave/row, 4x16 lanes, bf16 gathers ----------------
// WLO=1: also write lo-plane (only for the layers feeding the 3-term head GEMMs).

template <int WLO>
__global__ __launch_bounds__(256) void k_gat_agg(const unsigned short* __restrict__ gxl,
                                                 const unsigned short* __restrict__ gxr,
                                                 const float* __restrict__ att,
                                                 const float* __restrict__ bias,
                                                 const int* __restrict__ row_ptr,
                                                 const int* __restrict__ csr_src,
                                                 unsigned short* __restrict__ sh,
                                                 unsigned short* __restrict__ sl) {
  int gid = blockIdx.x * blockDim.x + threadIdx.x;
  int row = gid >> 6;
  int lane = gid & 63;
  if (row >= NN) return;
  int g = lane >> 4, j = lane & 15;
  int dbase = j * 8;

  float a[8], r[8];
  {
    float4 a0 = *(const float4*)&att[dbase];
    float4 a1 = *(const float4*)&att[dbase + 4];
    a[0] = a0.x; a[1] = a0.y; a[2] = a0.z; a[3] = a0.w;
    a[4] = a1.x; a[5] = a1.y; a[6] = a1.z; a[7] = a1.w;
    bf16x8 rv = *(const bf16x8*)&gxr[(size_t)row * 128 + dbase];
#pragma unroll
    for (int k = 0; k < 8; ++k) r[k] = bf2f((unsigned short)rv[k]);
  }

  float m = -INFINITY, d = 0.f;
  float acc[8] = {0.f, 0.f, 0.f, 0.f, 0.f, 0.f, 0.f, 0.f};
  int p0 = row_ptr[row], p1 = row_ptr[row + 1];

  for (int p = p0 + g; p < p1; p += 4) {
    int s = csr_src[p];
    bf16x8 xv = *(const bf16x8*)&gxl[(size_t)s * 128 + dbase];
    float v[8];
#pragma unroll
    for (int k = 0; k < 8; ++k) v[k] = bf2f((unsigned short)xv[k]);

    float e = 0.f;
#pragma unroll
    for (int k = 0; k < 8; ++k) {
      float t0 = v[k] + r[k];
      t0 = fmaxf(t0, 0.2f * t0);
      e = fmaf(t0, a[k], e);
    }
    e += __shfl_xor(e, 1);
    e += __shfl_xor(e, 2);
    e += __shfl_xor(e, 4);
    e += __shfl_xor(e, 8);

    float mn = fmaxf(m, e);
    float scl = __expf(m - mn);
    float w = __expf(e - mn);
    d = d * scl + w;
#pragma unroll
    for (int k = 0; k < 8; ++k) acc[k] = acc[k] * scl + w * v[k];
    m = mn;
  }

  float mo = fmaxf(m, __shfl_xor(m, 16));
  mo = fmaxf(mo, __shfl_xor(mo, 32));
  float scl = __expf(m - mo);
  d *= scl;
  d += __shfl_xor(d, 16);
  d += __shfl_xor(d, 32);
#pragma unroll
  for (int k = 0; k < 8; ++k) {
    acc[k] *= scl;
    acc[k] += __shfl_xor(acc[k], 16);
    acc[k] += __shfl_xor(acc[k], 32);
  }

  if (g == 0) {
    float inv = 1.f / d;
    float4 b0 = *(const float4*)&bias[dbase];
    float4 b1v = *(const float4*)&bias[dbase + 4];
    float bb[8] = {b0.x, b0.y, b0.z, b0.w, b1v.x, b1v.y, b1v.z, b1v.w};
    bf16x8 vh, vl;
#pragma unroll
    for (int k = 0; k < 8; ++k) {
      float h = gelu_exact(acc[k] * inv + bb[k]);
      unsigned short hi = f2bf(h);
      vh[k] = (short)hi;
      if (WLO) vl[k] = (short)f2bf(h - bf2f(hi));
    }
    *(bf16x8*)(sh + (size_t)row * 128 + dbase) = vh;
    if (WLO) *(bf16x8*)(sl + (size_t)row * 128 + dbase) = vl;
  }
}

// ---------------- host ----------------

static inline char* take(char*& p, size_t bytes) {
  char* r = p;
  p += (bytes + 255) & ~(size_t)255;
  return r;
}

extern "C" void kernel_launch(void* const* d_in, const int* in_sizes, int n_in,
                              void* d_out, int out_size, void* d_ws, size_t ws_size,
                              hipStream_t stream) {
  const float* x      = (const float*)d_in[0];
  const int*   ei     = (const int*)d_in[1];
  const float* eps    = (const float*)d_in[2];
  const float* encWl  = (const float*)d_in[3];
  const float* encWr  = (const float*)d_in[4];
  const float* encAtt = (const float*)d_in[5];
  const float* encB   = (const float*)d_in[6];
  const float* decWl  = (const float*)d_in[7];
  const float* decWr  = (const float*)d_in[8];
  const float* decAtt = (const float*)d_in[9];
  const float* decB   = (const float*)d_in[10];
  const float* W_mu   = (const float*)d_in[11];
  const float* b_mu   = (const float*)d_in[12];
  const float* W_ls   = (const float*)d_in[13];
  const float* b_ls   = (const float*)d_in[14];
  const float* W_out  = (const float*)d_in[15];
  const float* b_out  = (const float*)d_in[16];
  const float* W_deg  = (const float*)d_in[17];
  const float* b_deg  = (const float*)d_in[18];

  float* out    = (float*)d_out;
  float* x_rec  = out;
  float* z      = out + (size_t)ND;
  float* mu     = out + (size_t)2 * ND;
  float* logstd = out + (size_t)3 * ND;
  float* degp   = out + (size_t)4 * ND;

  char* p = (char*)d_ws;
  int* deg     = (int*)take(p, (size_t)NN * 4);
  int* row_ptr = (int*)take(p, (size_t)(NN + 1) * 4);
  int* cursor  = (int*)take(p, (size_t)NN * 4);
  int* bsum    = (int*)take(p, 64 * 4);
  int* csr_src = (int*)take(p, (size_t)ET * 4);
  unsigned short* gxl  = (unsigned short*)take(p, (size_t)MPAD * 128 * 2);
  unsigned short* gxr  = (unsigned short*)take(p, (size_t)MPAD * 128 * 2);
  unsigned short* stgh = (unsigned short*)take(p, (size_t)MPAD * 128 * 2);
  unsigned short* stgl = (unsigned short*)take(p, (size_t)MPAD * 128 * 2);
  unsigned short* wfh  = (unsigned short*)take(p, (size_t)19 * 16384 * 2);
  unsigned short* wfl  = (unsigned short*)take(p, (size_t)19 * 16384 * 2);

  const int nScan = (NN + SCAN_E - 1) / SCAN_E;   // 49
  const int gN    = (NN + 255) / 256;             // 391
  const int gET   = (ET + 255) / 256;             // 6641
  const int gMM   = MPAD / 128;                   // 782
  const int gWave = (NN * 64 + 255) / 256;        // 25000
  const int gXC   = (MPAD * 128 / 8 + 255) / 256; // 6256

  // CSR build
  k_zero_int<<<gN, 256, 0, stream>>>(deg, NN);
  k_count<<<gET, 256, 0, stream>>>(ei, deg);
  k_scan1<<<nScan, SCAN_T, 0, stream>>>(deg, bsum);
  k_scan2<<<1, 64, 0, stream>>>(bsum, nScan, row_ptr);
  k_scan3<<<nScan, SCAN_T, 0, stream>>>(deg, bsum, row_ptr);
  k_copy_int<<<gN, 256, 0, stream>>>(row_ptr, cursor, NN);
  k_scatter<<<gET, 256, 0, stream>>>(ei, cursor, csr_src);

  // weight frags + x stage
  k_wconv<<<152, 256, 0, stream>>>(encWl, encWr, decWl, decWr, W_mu, W_ls, W_out, wfh, wfl);
  k_xconv<<<gXC, 256, 0, stream>>>(x, stgh);

  const size_t WM = 16384;
  // encoder
  for (int l = 0; l < 4; ++l) {
    k_mmL<<<gMM, 512, 0, stream>>>(stgh,
                                   wfh + (size_t)l * WM, wfh + (size_t)(4 + l) * WM,
                                   gxl, gxr);
    if (l < 3)
      k_gat_agg<0><<<gWave, 256, 0, stream>>>(gxl, gxr, encAtt + (size_t)l * DD,
                                              encB + (size_t)l * DD, row_ptr, csr_src,
                                              stgh, stgl);
    else
      k_gat_agg<1><<<gWave, 256, 0, stream>>>(gxl, gxr, encAtt + (size_t)l * DD,
                                              encB + (size_t)l * DD, row_ptr, csr_src,
                                              stgh, stgl);
  }

  // heads: mu, logstd, z, z-stage(hi), degree head
  k_mmH<<<gMM, 512, 0, stream>>>(stgh, stgl,
                                 wfh + (size_t)16 * WM, wfl + (size_t)16 * WM,
                                 wfh + (size_t)17 * WM, wfl + (size_t)17 * WM,
                                 b_mu, b_ls, eps, W_deg, b_deg,
                                 mu, logstd, z, stgh, degp);

  // decoder
  for (int l = 0; l < 4; ++l) {
    k_mmL<<<gMM, 512, 0, stream>>>(stgh,
                                   wfh + (size_t)(8 + l) * WM, wfh + (size_t)(12 + l) * WM,
                                   gxl, gxr);
    if (l < 3)
      k_gat_agg<0><<<gWave, 256, 0, stream>>>(gxl, gxr, decAtt + (size_t)l * DD,
                                              decB + (size_t)l * DD, row_ptr, csr_src,
                                              stgh, stgl);
    else
      k_gat_agg<1><<<gWave, 256, 0, stream>>>(gxl, gxr, decAtt + (size_t)l * DD,
                                              decB + (size_t)l * DD, row_ptr, csr_src,
                                              stgh, stgl);
  }

  // x_rec
  k_mmO<<<gMM, 512, 0, stream>>>(stgh, stgl,
                                 wfh + (size_t)18 * WM, wfl + (size_t)18 * WM,
                                 b_out, x_rec);
}

// Round 9
// 1371.628 us; speedup vs baseline: 1.5201x; 1.0895x over previous
//
#include <hip/hip_runtime.h>
#include <math.h>

#define NN 100000
#define MPAD 100096
#define DD 128
#define EE 1600000
#define ET (EE + NN)
#define ND (NN * DD)

#define NBKT 782        // buckets of 128 dst each; 782*128 = 100096
#define IPB 16384       // items per block in hist/scatter passes
#define GSC 104         // ceil(ET/IPB)
#define BCAP 6144       // max edges per bucket (expected ~2200)

typedef short bf16x8 __attribute__((ext_vector_type(8)));
typedef float f32x4 __attribute__((ext_vector_type(4)));

static __device__ __forceinline__ unsigned short f2bf(float f) {
  unsigned int u = __float_as_uint(f);
  u += 0x7FFFu + ((u >> 16) & 1u);
  return (unsigned short)(u >> 16);
}
static __device__ __forceinline__ float bf2f(unsigned short h) {
  return __uint_as_float(((unsigned int)h) << 16);
}
static __device__ __forceinline__ float gelu_exact(float v) {
  return 0.5f * v * (1.f + erff(v * 0.7071067811865476f));
}

// ---------------- CSR build: bucketed counting sort ----------------

__global__ void k_zero_int(int* __restrict__ p, int n) {
  int i = blockIdx.x * blockDim.x + threadIdx.x;
  if (i < n) p[i] = 0;
}

// pass 1: per-block LDS histogram over buckets -> global bucket counts
__global__ __launch_bounds__(256) void kb_hist(const int* __restrict__ ei,
                                               int* __restrict__ cnt) {
  __shared__ int lc[NBKT];
  int t = threadIdx.x;
  for (int b = t; b < NBKT; b += 256) lc[b] = 0;
  __syncthreads();
  int i0 = blockIdx.x * IPB;
  int i1 = min(i0 + IPB, ET);
  for (int i = i0 + t; i < i1; i += 256) {
    int dst = (i < EE) ? ei[EE + i] : (i - EE);
    atomicAdd(&lc[dst >> 7], 1);
  }
  __syncthreads();
  for (int b = t; b < NBKT; b += 256) {
    int c = lc[b];
    if (c) atomicAdd(&cnt[b], c);
  }
}

// pass 2: scan bucket counts -> off[0..NBKT], cur[b]=off[b]
__global__ __launch_bounds__(256) void kb_scan(const int* __restrict__ cnt,
                                               int* __restrict__ off,
                                               int* __restrict__ cur) {
  __shared__ int sh[256];
  int t = threadIdx.x;
  int c[4]; int s = 0;
#pragma unroll
  for (int j = 0; j < 4; ++j) {
    int b = t * 4 + j;
    c[j] = s;
    int v = (b < NBKT) ? cnt[b] : 0;
    s += v;
  }
  sh[t] = s; __syncthreads();
  for (int o = 1; o < 256; o <<= 1) {
    int v = (t >= o) ? sh[t - o] : 0;
    __syncthreads();
    sh[t] += v;
    __syncthreads();
  }
  int excl = sh[t] - s;
#pragma unroll
  for (int j = 0; j < 4; ++j) {
    int b = t * 4 + j;
    if (b < NBKT) { off[b] = excl + c[j]; cur[b] = excl + c[j]; }
  }
  if (t == 255) off[NBKT] = excl + s;  // == ET
}

// pass 3: scatter edges into bucket-contiguous buf, LDS-staged runs per block
__global__ __launch_bounds__(256) void kb_scatter(const int* __restrict__ ei,
                                                  int* __restrict__ cur,
                                                  int* __restrict__ buf) {
  __shared__ int lc[NBKT];
  __shared__ int lb[NBKT];
  int t = threadIdx.x;
  for (int b = t; b < NBKT; b += 256) lc[b] = 0;
  __syncthreads();
  int i0 = blockIdx.x * IPB;
  int i1 = min(i0 + IPB, ET);
  for (int i = i0 + t; i < i1; i += 256) {
    int dst = (i < EE) ? ei[EE + i] : (i - EE);
    atomicAdd(&lc[dst >> 7], 1);
  }
  __syncthreads();
  for (int b = t; b < NBKT; b += 256) {
    int c = lc[b];
    lb[b] = c ? atomicAdd(&cur[b], c) : 0;
    lc[b] = 0;
  }
  __syncthreads();
  for (int i = i0 + t; i < i1; i += 256) {
    int src, dst;
    if (i < EE) { src = ei[i]; dst = ei[EE + i]; } else { src = i - EE; dst = src; }
    int b = dst >> 7;
    int l = atomicAdd(&lc[b], 1);
    buf[lb[b] + l] = src | ((dst & 127) << 17);
  }
}

// pass 4: per-bucket local sort -> coalesced csr_src + row_ptr
__global__ __launch_bounds__(256) void kb_fin(const int* __restrict__ buf,
                                              const int* __restrict__ off,
                                              int* __restrict__ csr_src,
                                              int* __restrict__ row_ptr) {
  __shared__ int ebuf[BCAP];
  __shared__ int osrc[BCAP];
  __shared__ int cnt[128], scn[128], lcur[128];
  int b = blockIdx.x;
  int base = off[b];
  int count = min(off[b + 1] - base, BCAP);
  int t = threadIdx.x;
  if (t < 128) { cnt[t] = 0; lcur[t] = 0; }
  __syncthreads();
  for (int i = t; i < count; i += 256) {
    int w = buf[base + i];
    ebuf[i] = w;
    atomicAdd(&cnt[(w >> 17) & 127], 1);
  }
  __syncthreads();
  if (t < 128) scn[t] = cnt[t];
  __syncthreads();
  for (int o = 1; o < 128; o <<= 1) {
    int v = 0;
    if (t < 128 && t >= o) v = scn[t - o];
    __syncthreads();
    if (t < 128) scn[t] += v;
    __syncthreads();
  }
  // exclusive prefix = scn[d] - cnt[d]
  for (int i = t; i < count; i += 256) {
    int w = ebuf[i];
    int d = (w >> 17) & 127;
    int l = atomicAdd(&lcur[d], 1);
    osrc[(scn[d] - cnt[d]) + l] = w & 0x1FFFF;
  }
  __syncthreads();
  for (int i = t; i < count; i += 256) csr_src[base + i] = osrc[i];
  if (t < 128) {
    int gd = b * 128 + t;
    if (gd <= NN) row_ptr[gd] = base + scn[t] - cnt[t];
  }
}

// ---------------- weight fragment precompute (19 mats of 128x128) ----------------

__global__ __launch_bounds__(256) void k_wconv(const float* __restrict__ encWl,
                                               const float* __restrict__ encWr,
                                               const float* __restrict__ decWl,
                                               const float* __restrict__ decWr,
                                               const float* __restrict__ Wmu,
                                               const float* __restrict__ Wls,
                                               const float* __restrict__ Wout,
                                               unsigned short* __restrict__ wfh,
                                               unsigned short* __restrict__ wfl) {
  int wid = (blockIdx.x * 256 + threadIdx.x) >> 6;
  int lane = threadIdx.x & 63;
  if (wid >= 19 * 32) return;
  int mat = wid >> 5;
  int sub = wid & 31;
  const float* W;
  if (mat < 4) W = encWl + (size_t)mat * 16384;
  else if (mat < 8) W = encWr + (size_t)(mat - 4) * 16384;
  else if (mat < 12) W = decWl + (size_t)(mat - 8) * 16384;
  else if (mat < 16) W = decWr + (size_t)(mat - 12) * 16384;
  else if (mat == 16) W = Wmu;
  else if (mat == 17) W = Wls;
  else W = Wout;
  int t = sub >> 3, c = sub & 7;
  int col = c * 16 + (lane & 15);
  int k0 = t * 32 + (lane >> 4) * 8;
  bf16x8 vh, vl;
#pragma unroll
  for (int j = 0; j < 8; ++j) {
    float w = W[(size_t)(k0 + j) * 128 + col];
    unsigned short h = f2bf(w);
    vh[j] = (short)h;
    vl[j] = (short)f2bf(w - bf2f(h));
  }
  size_t base = ((size_t)wid * 64 + lane) * 8;
  *(bf16x8*)(wfh + base) = vh;
  *(bf16x8*)(wfl + base) = vl;
}

// ---------------- x -> bf16 stage (hi only) ----------------

__global__ void k_xconv(const float* __restrict__ x, unsigned short* __restrict__ sh) {
  int i = blockIdx.x * blockDim.x + threadIdx.x;
  if (i >= MPAD * 128 / 8) return;
  size_t base = (size_t)i * 8;
  float v[8];
  if (base < (size_t)ND) {
    float4 f0 = *(const float4*)(x + base);
    float4 f1 = *(const float4*)(x + base + 4);
    v[0] = f0.x; v[1] = f0.y; v[2] = f0.z; v[3] = f0.w;
    v[4] = f1.x; v[5] = f1.y; v[6] = f1.z; v[7] = f1.w;
  } else {
#pragma unroll
    for (int j = 0; j < 8; ++j) v[j] = 0.f;
  }
  bf16x8 vh;
#pragma unroll
  for (int j = 0; j < 8; ++j) vh[j] = (short)f2bf(v[j]);
  *(bf16x8*)(sh + base) = vh;
}

// ---------------- layer dual GEMM: 1-term bf16, bf16 out ----------------

__global__ __launch_bounds__(512, 4) void k_mmL(const unsigned short* __restrict__ Ah,
                                                const unsigned short* __restrict__ w1,
                                                const unsigned short* __restrict__ w2,
                                                unsigned short* __restrict__ o1,
                                                unsigned short* __restrict__ o2) {
  __shared__ float lds[128 * 132];  // 67.6 KB
  unsigned short* lw = (unsigned short*)lds;
  int tid = threadIdx.x;
  {
    int4* d = (int4*)lw;
    const int4* s1 = (const int4*)w1;
    const int4* s2 = (const int4*)w2;
#pragma unroll
    for (int i = 0; i < 4; ++i) {
      d[tid + i * 512] = s1[tid + i * 512];
      d[2048 + tid + i * 512] = s2[tid + i * 512];
    }
  }
  int wv = tid >> 6, lane = tid & 63;
  int lrow = lane & 15, lk = lane >> 4;
  int rbase = blockIdx.x * 128 + wv * 16;

  bf16x8 a_h[4];
  const unsigned short* ap = Ah + (size_t)(rbase + lrow) * 128 + lk * 8;
#pragma unroll
  for (int t = 0; t < 4; ++t) a_h[t] = *(const bf16x8*)(ap + t * 32);
  __syncthreads();

  f32x4 acc1[8], acc2[8];
#pragma unroll
  for (int c = 0; c < 8; ++c) {
    acc1[c] = (f32x4){0.f, 0.f, 0.f, 0.f};
    acc2[c] = (f32x4){0.f, 0.f, 0.f, 0.f};
  }
#pragma unroll
  for (int t = 0; t < 4; ++t) {
#pragma unroll
    for (int c = 0; c < 8; ++c) {
      int fo = ((t * 8 + c) * 64 + lane) * 8;
      bf16x8 wf1 = *(const bf16x8*)(lw + fo);
      bf16x8 wf2 = *(const bf16x8*)(lw + 16384 + fo);
      acc1[c] = __builtin_amdgcn_mfma_f32_16x16x32_bf16(a_h[t], wf1, acc1[c], 0, 0, 0);
      acc2[c] = __builtin_amdgcn_mfma_f32_16x16x32_bf16(a_h[t], wf2, acc2[c], 0, 0, 0);
    }
  }
  __syncthreads();  // weights dead; LDS becomes transpose buffer

  int lr = tid >> 2, cb = (tid & 3) << 5;
  size_t o = ((size_t)blockIdx.x * 128 + lr) * 128 + cb;

#pragma unroll
  for (int out = 0; out < 2; ++out) {
#pragma unroll
    for (int c = 0; c < 8; ++c)
#pragma unroll
      for (int r = 0; r < 4; ++r)
        lds[(wv * 16 + lk * 4 + r) * 132 + c * 16 + lrow] = out ? acc2[c][r] : acc1[c][r];
    __syncthreads();
    {
      unsigned short* dst = out ? o2 : o1;
      const float* sp = &lds[lr * 132 + cb];
#pragma unroll
      for (int i = 0; i < 4; ++i) {
        union { unsigned short u[8]; int4 v; } pk;
#pragma unroll
        for (int j = 0; j < 8; ++j) pk.u[j] = f2bf(sp[i * 8 + j]);
        *(int4*)&dst[o + i * 8] = pk.v;
      }
    }
    __syncthreads();
  }
}

// ---------------- head kernel: mu, logstd, z, z-stage(hi), degree pred ----------------

__global__ __launch_bounds__(512, 3) void k_mmH(const unsigned short* Ah,
                                                const unsigned short* Al,
                                                const unsigned short* __restrict__ w1h,
                                                const unsigned short* __restrict__ w1l,
                                                const unsigned short* __restrict__ w2h,
                                                const unsigned short* __restrict__ w2l,
                                                const float* __restrict__ b1,
                                                const float* __restrict__ b2,
                                                const float* __restrict__ eps,
                                                const float* __restrict__ Wd,
                                                const float* __restrict__ bd,
                                                float* __restrict__ mu,
                                                float* __restrict__ logstd,
                                                float* __restrict__ Z,
                                                unsigned short* Zh,
                                                float* __restrict__ degp) {
  __shared__ float lds[128 * 132];
  unsigned short* lw = (unsigned short*)lds;
  int tid = threadIdx.x;
  int wv = tid >> 6, lane = tid & 63;
  int lrow = lane & 15, lk = lane >> 4;
  int rbase = blockIdx.x * 128 + wv * 16;

  {
    int4* d = (int4*)lw;
#pragma unroll
    for (int i = 0; i < 4; ++i) {
      d[tid + i * 512] = ((const int4*)w1h)[tid + i * 512];
      d[2048 + tid + i * 512] = ((const int4*)w1l)[tid + i * 512];
    }
  }
  bf16x8 a_h[4], a_l[4];
  const unsigned short* ap = Ah + (size_t)(rbase + lrow) * 128 + lk * 8;
  const unsigned short* alp = Al + (size_t)(rbase + lrow) * 128 + lk * 8;
#pragma unroll
  for (int t = 0; t < 4; ++t) {
    a_h[t] = *(const bf16x8*)(ap + t * 32);
    a_l[t] = *(const bf16x8*)(alp + t * 32);
  }
  __syncthreads();

  f32x4 acc1[8];
#pragma unroll
  for (int c = 0; c < 8; ++c) acc1[c] = (f32x4){0.f, 0.f, 0.f, 0.f};
#pragma unroll
  for (int t = 0; t < 4; ++t) {
#pragma unroll
    for (int c = 0; c < 8; ++c) {
      int fo = ((t * 8 + c) * 64 + lane) * 8;
      bf16x8 wh = *(const bf16x8*)(lw + fo);
      bf16x8 wl = *(const bf16x8*)(lw + 16384 + fo);
      acc1[c] = __builtin_amdgcn_mfma_f32_16x16x32_bf16(a_h[t], wh, acc1[c], 0, 0, 0);
      acc1[c] = __builtin_amdgcn_mfma_f32_16x16x32_bf16(a_l[t], wh, acc1[c], 0, 0, 0);
      acc1[c] = __builtin_amdgcn_mfma_f32_16x16x32_bf16(a_h[t], wl, acc1[c], 0, 0, 0);
    }
  }
  __syncthreads();

  {
    int4* d = (int4*)lw;
#pragma unroll
    for (int i = 0; i < 4; ++i) {
      d[tid + i * 512] = ((const int4*)w2h)[tid + i * 512];
      d[2048 + tid + i * 512] = ((const int4*)w2l)[tid + i * 512];
    }
  }
  __syncthreads();

  f32x4 acc2[8];
#pragma unroll
  for (int c = 0; c < 8; ++c) acc2[c] = (f32x4){0.f, 0.f, 0.f, 0.f};
#pragma unroll
  for (int t = 0; t < 4; ++t) {
#pragma unroll
    for (int c = 0; c < 8; ++c) {
      int fo = ((t * 8 + c) * 64 + lane) * 8;
      bf16x8 wh = *(const bf16x8*)(lw + fo);
      bf16x8 wl = *(const bf16x8*)(lw + 16384 + fo);
      acc2[c] = __builtin_amdgcn_mfma_f32_16x16x32_bf16(a_h[t], wh, acc2[c], 0, 0, 0);
      acc2[c] = __builtin_amdgcn_mfma_f32_16x16x32_bf16(a_l[t], wh, acc2[c], 0, 0, 0);
      acc2[c] = __builtin_amdgcn_mfma_f32_16x16x32_bf16(a_h[t], wl, acc2[c], 0, 0, 0);
    }
  }
  __syncthreads();

  int lr = tid >> 2, cb = (tid & 3) << 5;
  int grow = blockIdx.x * 128 + lr;
  size_t o = (size_t)grow * 128 + cb;

#pragma unroll
  for (int c = 0; c < 8; ++c)
#pragma unroll
    for (int r = 0; r < 4; ++r)
      lds[(wv * 16 + lk * 4 + r) * 132 + c * 16 + lrow] = acc1[c][r];
  __syncthreads();
  float4 mureg[8];
  if (grow < NN) {
    const float* sp = &lds[lr * 132 + cb];
#pragma unroll
    for (int i = 0; i < 8; ++i) {
      float4 v = *(const float4*)(sp + i * 4);
      float4 b4 = *(const float4*)&b1[cb + i * 4];
      v.x += b4.x; v.y += b4.y; v.z += b4.z; v.w += b4.w;
      mureg[i] = v;
      *(float4*)&mu[o + i * 4] = v;
    }
  }
  __syncthreads();
#pragma unroll
  for (int c = 0; c < 8; ++c)
#pragma unroll
    for (int r = 0; r < 4; ++r)
      lds[(wv * 16 + lk * 4 + r) * 132 + c * 16 + lrow] = acc2[c][r];
  __syncthreads();
  float s_deg = 0.f;
  if (grow < NN) {
    const float* sp = &lds[lr * 132 + cb];
#pragma unroll
    for (int i = 0; i < 8; ++i) {
      float4 v = *(const float4*)(sp + i * 4);
      float4 b4 = *(const float4*)&b2[cb + i * 4];
      float4 ls;
      ls.x = fminf(v.x + b4.x, 10.f);
      ls.y = fminf(v.y + b4.y, 10.f);
      ls.z = fminf(v.z + b4.z, 10.f);
      ls.w = fminf(v.w + b4.w, 10.f);
      *(float4*)&logstd[o + i * 4] = ls;
      float4 e4 = *(const float4*)&eps[o + i * 4];
      float4 z4;
      z4.x = fmaf(e4.x, expf(ls.x), mureg[i].x);
      z4.y = fmaf(e4.y, expf(ls.y), mureg[i].y);
      z4.z = fmaf(e4.z, expf(ls.z), mureg[i].z);
      z4.w = fmaf(e4.w, expf(ls.w), mureg[i].w);
      *(float4*)&Z[o + i * 4] = z4;
      ushort4 hh;
      hh.x = f2bf(z4.x); hh.y = f2bf(z4.y); hh.z = f2bf(z4.z); hh.w = f2bf(z4.w);
      *(ushort4*)&Zh[o + i * 4] = hh;
      float4 wd = *(const float4*)&Wd[cb + i * 4];
      s_deg += z4.x * wd.x + z4.y * wd.y + z4.z * wd.z + z4.w * wd.w;
    }
  }
  s_deg += __shfl_xor(s_deg, 1);
  s_deg += __shfl_xor(s_deg, 2);
  if (grow < NN && (tid & 3) == 0) degp[grow] = s_deg + bd[0];
}

// ---------------- output GEMM: x_rec = A@W + b, 3-term split, fp32 out ----------------

__global__ __launch_bounds__(512, 4) void k_mmO(const unsigned short* __restrict__ Ah,
                                                const unsigned short* __restrict__ Al,
                                                const unsigned short* __restrict__ wh,
                                                const unsigned short* __restrict__ wl,
                                                const float* __restrict__ bias,
                                                float* __restrict__ C) {
  __shared__ float lds[128 * 132];
  unsigned short* lw = (unsigned short*)lds;
  int tid = threadIdx.x;
  {
    int4* d = (int4*)lw;
#pragma unroll
    for (int i = 0; i < 4; ++i) {
      d[tid + i * 512] = ((const int4*)wh)[tid + i * 512];
      d[2048 + tid + i * 512] = ((const int4*)wl)[tid + i * 512];
    }
  }
  int wv = tid >> 6, lane = tid & 63;
  int lrow = lane & 15, lk = lane >> 4;
  int rbase = blockIdx.x * 128 + wv * 16;

  bf16x8 a_h[4], a_l[4];
  const unsigned short* ap = Ah + (size_t)(rbase + lrow) * 128 + lk * 8;
  const unsigned short* alp = Al + (size_t)(rbase + lrow) * 128 + lk * 8;
#pragma unroll
  for (int t = 0; t < 4; ++t) {
    a_h[t] = *(const bf16x8*)(ap + t * 32);
    a_l[t] = *(const bf16x8*)(alp + t * 32);
  }
  __syncthreads();

  f32x4 acc[8];
#pragma unroll
  for (int c = 0; c < 8; ++c) acc[c] = (f32x4){0.f, 0.f, 0.f, 0.f};
#pragma unroll
  for (int t = 0; t < 4; ++t) {
#pragma unroll
    for (int c = 0; c < 8; ++c) {
      int fo = ((t * 8 + c) * 64 + lane) * 8;
      bf16x8 whf = *(const bf16x8*)(lw + fo);
      bf16x8 wlf = *(const bf16x8*)(lw + 16384 + fo);
      acc[c] = __builtin_amdgcn_mfma_f32_16x16x32_bf16(a_h[t], whf, acc[c], 0, 0, 0);
      acc[c] = __builtin_amdgcn_mfma_f32_16x16x32_bf16(a_l[t], whf, acc[c], 0, 0, 0);
      acc[c] = __builtin_amdgcn_mfma_f32_16x16x32_bf16(a_h[t], wlf, acc[c], 0, 0, 0);
    }
  }
  __syncthreads();

#pragma unroll
  for (int c = 0; c < 8; ++c)
#pragma unroll
    for (int r = 0; r < 4; ++r)
      lds[(wv * 16 + lk * 4 + r) * 132 + c * 16 + lrow] = acc[c][r];
  __syncthreads();
  int lr = tid >> 2, cb = (tid & 3) << 5;
  int grow = blockIdx.x * 128 + lr;
  if (grow < NN) {
    size_t o = (size_t)grow * 128 + cb;
    const float* sp = &lds[lr * 132 + cb];
#pragma unroll
    for (int i = 0; i < 8; ++i) {
      float4 v = *(const float4*)(sp + i * 4);
      float4 b4 = *(const float4*)&bias[cb + i * 4];
      v.x += b4.x; v.y += b4.y; v.z += b4.z; v.w += b4.w;
      *(float4*)&C[o + i * 4] = v;
    }
  }
}

// ---------------- GATv2 aggregation: wave/row, 4x16 lanes, bf16 gathers ----------------

template <int WLO>
__global__ __launch_bounds__(256) void k_gat_agg(const unsigned short* __restrict__ gxl,
                                                 const unsigned short* __restrict__ gxr,
                                                 const float* __restrict__ att,
                                                 const float* __restrict__ bias,
                                                 const int* __restrict__ row_ptr,
                                                 const int* __restrict__ csr_src,
                                                 unsigned short* __restrict__ sh,
                                                 unsigned short* __restrict__ sl) {
  int gid = blockIdx.x * blockDim.x + threadIdx.x;
  int row = gid >> 6;
  int lane = gid & 63;
  if (row >= NN) return;
  int g = lane >> 4, j = lane & 15;
  int dbase = j * 8;

  float a[8], r[8];
  {
    float4 a0 = *(const float4*)&att[dbase];
    float4 a1 = *(const float4*)&att[dbase + 4];
    a[0] = a0.x; a[1] = a0.y; a[2] = a0.z; a[3] = a0.w;
    a[4] = a1.x; a[5] = a1.y; a[6] = a1.z; a[7] = a1.w;
    bf16x8 rv = *(const bf16x8*)&gxr[(size_t)row * 128 + dbase];
#pragma unroll
    for (int k = 0; k < 8; ++k) r[k] = bf2f((unsigned short)rv[k]);
  }

  float m = -INFINITY, d = 0.f;
  float acc[8] = {0.f, 0.f, 0.f, 0.f, 0.f, 0.f, 0.f, 0.f};
  int p0 = row_ptr[row], p1 = row_ptr[row + 1];

  for (int p = p0 + g; p < p1; p += 4) {
    int s = csr_src[p];
    bf16x8 xv = *(const bf16x8*)&gxl[(size_t)s * 128 + dbase];
    float v[8];
#pragma unroll
    for (int k = 0; k < 8; ++k) v[k] = bf2f((unsigned short)xv[k]);

    float e = 0.f;
#pragma unroll
    for (int k = 0; k < 8; ++k) {
      float t0 = v[k] + r[k];
      t0 = fmaxf(t0, 0.2f * t0);
      e = fmaf(t0, a[k], e);
    }
    e += __shfl_xor(e, 1);
    e += __shfl_xor(e, 2);
    e += __shfl_xor(e, 4);
    e += __shfl_xor(e, 8);

    float mn = fmaxf(m, e);
    float scl = __expf(m - mn);
    float w = __expf(e - mn);
    d = d * scl + w;
#pragma unroll
    for (int k = 0; k < 8; ++k) acc[k] = acc[k] * scl + w * v[k];
    m = mn;
  }

  float mo = fmaxf(m, __shfl_xor(m, 16));
  mo = fmaxf(mo, __shfl_xor(mo, 32));
  float scl = __expf(m - mo);
  d *= scl;
  d += __shfl_xor(d, 16);
  d += __shfl_xor(d, 32);
#pragma unroll
  for (int k = 0; k < 8; ++k) {
    acc[k] *= scl;
    acc[k] += __shfl_xor(acc[k], 16);
    acc[k] += __shfl_xor(acc[k], 32);
  }

  if (g == 0) {
    float inv = 1.f / d;
    float4 b0 = *(const float4*)&bias[dbase];
    float4 b1v = *(const float4*)&bias[dbase + 4];
    float bb[8] = {b0.x, b0.y, b0.z, b0.w, b1v.x, b1v.y, b1v.z, b1v.w};
    bf16x8 vh, vl;
#pragma unroll
    for (int k = 0; k < 8; ++k) {
      float h = gelu_exact(acc[k] * inv + bb[k]);
      unsigned short hi = f2bf(h);
      vh[k] = (short)hi;
      if (WLO) vl[k] = (short)f2bf(h - bf2f(hi));
    }
    *(bf16x8*)(sh + (size_t)row * 128 + dbase) = vh;
    if (WLO) *(bf16x8*)(sl + (size_t)row * 128 + dbase) = vl;
  }
}

// ---------------- host ----------------

static inline char* take(char*& p, size_t bytes) {
  char* r = p;
  p += (bytes + 255) & ~(size_t)255;
  return r;
}

extern "C" void kernel_launch(void* const* d_in, const int* in_sizes, int n_in,
                              void* d_out, int out_size, void* d_ws, size_t ws_size,
                              hipStream_t stream) {
  const float* x      = (const float*)d_in[0];
  const int*   ei     = (const int*)d_in[1];
  const float* eps    = (const float*)d_in[2];
  const float* encWl  = (const float*)d_in[3];
  const float* encWr  = (const float*)d_in[4];
  const float* encAtt = (const float*)d_in[5];
  const float* encB   = (const float*)d_in[6];
  const float* decWl  = (const float*)d_in[7];
  const float* decWr  = (const float*)d_in[8];
  const float* decAtt = (const float*)d_in[9];
  const float* decB   = (const float*)d_in[10];
  const float* W_mu   = (const float*)d_in[11];
  const float* b_mu   = (const float*)d_in[12];
  const float* W_ls   = (const float*)d_in[13];
  const float* b_ls   = (const float*)d_in[14];
  const float* W_out  = (const float*)d_in[15];
  const float* b_out  = (const float*)d_in[16];
  const float* W_deg  = (const float*)d_in[17];
  const float* b_deg  = (const float*)d_in[18];

  float* out    = (float*)d_out;
  float* x_rec  = out;
  float* z      = out + (size_t)ND;
  float* mu     = out + (size_t)2 * ND;
  float* logstd = out + (size_t)3 * ND;
  float* degp   = out + (size_t)4 * ND;

  char* p = (char*)d_ws;
  int* bktcnt  = (int*)take(p, 1024 * 4);
  int* bktoff  = (int*)take(p, 1024 * 4);
  int* bktcur  = (int*)take(p, 1024 * 4);
  int* ebuf_g  = (int*)take(p, (size_t)ET * 4);
  int* row_ptr = (int*)take(p, (size_t)(NN + 1) * 4);
  int* csr_src = (int*)take(p, (size_t)ET * 4);
  unsigned short* gxl  = (unsigned short*)take(p, (size_t)MPAD * 128 * 2);
  unsigned short* gxr  = (unsigned short*)take(p, (size_t)MPAD * 128 * 2);
  unsigned short* stgh = (unsigned short*)take(p, (size_t)MPAD * 128 * 2);
  unsigned short* stgl = (unsigned short*)take(p, (size_t)MPAD * 128 * 2);
  unsigned short* wfh  = (unsigned short*)take(p, (size_t)19 * 16384 * 2);
  unsigned short* wfl  = (unsigned short*)take(p, (size_t)19 * 16384 * 2);

  const int gMM   = MPAD / 128;                   // 782
  const int gWave = (NN * 64 + 255) / 256;        // 25000
  const int gXC   = (MPAD * 128 / 8 + 255) / 256; // 6256

  // CSR build: bucketed counting sort
  k_zero_int<<<4, 256, 0, stream>>>(bktcnt, 1024);
  kb_hist<<<GSC, 256, 0, stream>>>(ei, bktcnt);
  kb_scan<<<1, 256, 0, stream>>>(bktcnt, bktoff, bktcur);
  kb_scatter<<<GSC, 256, 0, stream>>>(ei, bktcur, ebuf_g);
  kb_fin<<<NBKT, 256, 0, stream>>>(ebuf_g, bktoff, csr_src, row_ptr);

  // weight frags + x stage
  k_wconv<<<152, 256, 0, stream>>>(encWl, encWr, decWl, decWr, W_mu, W_ls, W_out, wfh, wfl);
  k_xconv<<<gXC, 256, 0, stream>>>(x, stgh);

  const size_t WM = 16384;
  // encoder
  for (int l = 0; l < 4; ++l) {
    k_mmL<<<gMM, 512, 0, stream>>>(stgh,
                                   wfh + (size_t)l * WM, wfh + (size_t)(4 + l) * WM,
                                   gxl, gxr);
    if (l < 3)
      k_gat_agg<0><<<gWave, 256, 0, stream>>>(gxl, gxr, encAtt + (size_t)l * DD,
                                              encB + (size_t)l * DD, row_ptr, csr_src,
                                              stgh, stgl);
    else
      k_gat_agg<1><<<gWave, 256, 0, stream>>>(gxl, gxr, encAtt + (size_t)l * DD,
                                              encB + (size_t)l * DD, row_ptr, csr_src,
                                              stgh, stgl);
  }

  // heads: mu, logstd, z, z-stage(hi), degree head
  k_mmH<<<gMM, 512, 0, stream>>>(stgh, stgl,
                                 wfh + (size_t)16 * WM, wfl + (size_t)16 * WM,
                                 wfh + (size_t)17 * WM, wfl + (size_t)17 * WM,
                                 b_mu, b_ls, eps, W_deg, b_deg,
                                 mu, logstd, z, stgh, degp);

  // decoder
  for (int l = 0; l < 4; ++l) {
    k_mmL<<<gMM, 512, 0, stream>>>(stgh,
                                   wfh + (size_t)(8 + l) * WM, wfh + (size_t)(12 + l) * WM,
                                   gxl, gxr);
    if (l < 3)
      k_gat_agg<0><<<gWave, 256, 0, stream>>>(gxl, gxr, decAtt + (size_t)l * DD,
                                              decB + (size_t)l * DD, row_ptr, csr_src,
                                              stgh, stgl);
    else
      k_gat_agg<1><<<gWave, 256, 0, stream>>>(gxl, gxr, decAtt + (size_t)l * DD,
                                              decB + (size_t)l * DD, row_ptr, csr_src,
                                              stgh, stgl);
  }

  // x_rec
  k_mmO<<<gMM, 512, 0, stream>>>(stgh, stgl,
                                 wfh + (size_t)18 * WM, wfl + (size_t)18 * WM,
                                 b_out, x_rec);
}